// Round 2
// baseline (620.128 us; speedup 1.0000x reference)
//
#include <hip/hip_runtime.h>
#include <hip/hip_bf16.h>

// GATv2 x2 on MI355X — all fp32 (reference dtypes). Pipeline:
//  1. gemm1: xl1/xr1 = x @ W1l / W1r          (fp32, [N,512] each)
//  2. CSR build: count deg(dst) -> scan -> scatter edges sorted by dst
//  3. edge1: alpha1[e,h] = <lrelu(xl1[s]+xr1[d]), att1[h]>   (wave per edge)
//  4. node1: per-dst softmax over incoming edges + weighted agg + elu -> h1
//  5. gemm2: xw2 = h1 @ [W2l | W2r]           ([N,64]: cols 0-31 xl2, 32-63 xr2)
//  6. edge2: alpha2[e] (32 lanes per edge)
//  7. node2: softmax-agg + bias + log_softmax over 32 ch -> fp32 out

constexpr int N_NODES = 10000;
constexpr int N_EDGES = 320000;
constexpr int ET      = N_EDGES + N_NODES;   // 330000 incl. self loops
constexpr float NEG_SLOPE = 0.2f;

// ---------------- CSR build ----------------

__global__ void k_count(const int* __restrict__ ei, int* __restrict__ deg) {
    int e = blockIdx.x * 256 + threadIdx.x;
    if (e >= ET) return;
    int d = (e < N_EDGES) ? ei[N_EDGES + e] : (e - N_EDGES);
    atomicAdd(&deg[d], 1);
}

__global__ __launch_bounds__(1024) void k_scan(const int* __restrict__ deg,
                                               int* __restrict__ offs) {
    __shared__ int part[1024];
    const int CH = 10;                       // ceil(10000/1024)
    int t = threadIdx.x;
    int base = t * CH;
    int loc[CH];
    int s = 0;
    for (int i = 0; i < CH; ++i) {
        int idx = base + i;
        int v = (idx < N_NODES) ? deg[idx] : 0;
        loc[i] = s; s += v;
    }
    part[t] = s;
    __syncthreads();
    for (int o = 1; o < 1024; o <<= 1) {
        int add = (t >= o) ? part[t - o] : 0;
        __syncthreads();
        part[t] += add;
        __syncthreads();
    }
    int excl = part[t] - s;
    for (int i = 0; i < CH; ++i) {
        int idx = base + i;
        if (idx < N_NODES) offs[idx] = excl + loc[i];
    }
    if (t == 1023) offs[N_NODES] = part[1023];
}

__global__ void k_scatter(const int* __restrict__ ei, const int* __restrict__ offs,
                          int* __restrict__ cursor, int* __restrict__ ssrc,
                          int* __restrict__ sdst) {
    int e = blockIdx.x * 256 + threadIdx.x;
    if (e >= ET) return;
    int s, d;
    if (e < N_EDGES) { s = ei[e]; d = ei[N_EDGES + e]; }
    else             { s = d = e - N_EDGES; }
    int pos = offs[d] + atomicAdd(&cursor[d], 1);
    ssrc[pos] = s; sdst[pos] = d;
}

// ---------------- layer 1 ----------------

// 16 rows x 1024 cols (W1l||W1r fused) per block, 256 threads, 4 cols/thread.
__global__ __launch_bounds__(256) void k_gemm1(const float* __restrict__ x,
        const float* __restrict__ Wl, const float* __restrict__ Wr,
        float* __restrict__ xl1, float* __restrict__ xr1) {
    __shared__ float xs[16 * 256];
    int t = threadIdx.x;
    int row0 = blockIdx.x * 16;
    const float4* xsrc = reinterpret_cast<const float4*>(x + (size_t)row0 * 256);
    float4* xdst = reinterpret_cast<float4*>(xs);
    for (int i = t; i < 16 * 64; i += 256) xdst[i] = xsrc[i];
    __syncthreads();
    int cb = t * 4;
    const float* W = (cb < 512) ? (Wl + cb) : (Wr + (cb - 512));
    float acc[16][4];
    for (int r = 0; r < 16; ++r)
        for (int j = 0; j < 4; ++j) acc[r][j] = 0.f;
    for (int k = 0; k < 256; ++k) {
        float4 w = *reinterpret_cast<const float4*>(W + (size_t)k * 512);
#pragma unroll
        for (int r = 0; r < 16; ++r) {
            float a = xs[r * 256 + k];
            acc[r][0] += a * w.x; acc[r][1] += a * w.y;
            acc[r][2] += a * w.z; acc[r][3] += a * w.w;
        }
    }
    float* outp = (cb < 512) ? (xl1 + cb) : (xr1 + (cb - 512));
    for (int r = 0; r < 16; ++r) {
        float4 v = make_float4(acc[r][0], acc[r][1], acc[r][2], acc[r][3]);
        *reinterpret_cast<float4*>(outp + (size_t)(row0 + r) * 512) = v;
    }
}

// one wave per edge; lane l covers channel l of every head
__global__ __launch_bounds__(256) void k_edge1(const int* __restrict__ ssrc,
        const int* __restrict__ sdst, const float* __restrict__ xl1,
        const float* __restrict__ xr1, const float* __restrict__ att1,
        float* __restrict__ alpha1) {
    __shared__ float att[512];
    int t = threadIdx.x;
    att[t]       = att1[t];
    att[t + 256] = att1[t + 256];
    __syncthreads();
    int wave = t >> 6, lane = t & 63;
    int pos = blockIdx.x * 4 + wave;
    if (pos >= ET) return;
    int s = ssrc[pos], d = sdst[pos];
    const float* xls = xl1 + (size_t)s * 512;
    const float* xrd = xr1 + (size_t)d * 512;
    float p[8];
#pragma unroll
    for (int h = 0; h < 8; ++h) {
        int idx = h * 64 + lane;
        float a = xls[idx] + xrd[idx];
        a = (a > 0.f) ? a : NEG_SLOPE * a;
        p[h] = a * att[idx];
    }
#pragma unroll
    for (int h = 0; h < 8; ++h) {
        float v = p[h];
        for (int o = 32; o; o >>= 1) v += __shfl_down(v, o);
        if (lane == 0) alpha1[(size_t)pos * 8 + h] = v;
    }
}

// one block (512 thr = 8 waves) per node; wave h owns head h
__global__ __launch_bounds__(512) void k_node1(const int* __restrict__ offs,
        const int* __restrict__ ssrc, const float* __restrict__ alpha1,
        const float* __restrict__ xl1, const float* __restrict__ b1,
        float* __restrict__ h1) {
    __shared__ float sm_m[8], sm_inv[8];
    int n = blockIdx.x;
    int t = threadIdx.x;
    int beg = offs[n], dcnt = offs[n + 1] - beg;
    int h = t >> 6, lane = t & 63;
    // softmax stats for head h
    float m = -1e30f;
    for (int i = lane; i < dcnt; i += 64)
        m = fmaxf(m, alpha1[(size_t)(beg + i) * 8 + h]);
    for (int o = 32; o; o >>= 1) m = fmaxf(m, __shfl_down(m, o));
    m = __shfl(m, 0);
    float s = 0.f;
    for (int i = lane; i < dcnt; i += 64)
        s += __expf(alpha1[(size_t)(beg + i) * 8 + h] - m);
    for (int o = 32; o; o >>= 1) s += __shfl_down(s, o);
    if (lane == 0) { sm_m[h] = m; sm_inv[h] = 1.f / (s + 1e-16f); }
    __syncthreads();
    float mh = sm_m[h], inv = sm_inv[h];
    // aggregation: thread t -> (head h, channel lane)
    float acc = 0.f;
    for (int i = 0; i < dcnt; ++i) {
        int pos = beg + i;
        float w = __expf(alpha1[(size_t)pos * 8 + h] - mh);
        int sn = ssrc[pos];
        acc += w * xl1[(size_t)sn * 512 + h * 64 + lane];
    }
    float v = acc * inv + b1[t];
    v = (v > 0.f) ? v : expm1f(v);      // elu
    h1[(size_t)n * 512 + t] = v;
}

// ---------------- layer 2 ----------------

// 4 rows x 64 cols (W2l||W2r fused) per block, 256 threads
__global__ __launch_bounds__(256) void k_gemm2(const float* __restrict__ h1,
        const float* __restrict__ Wl, const float* __restrict__ Wr,
        float* __restrict__ xw2) {
    __shared__ float hs[4 * 512];
    int t = threadIdx.x;
    int n0 = blockIdx.x * 4;
    const float4* hsrc = reinterpret_cast<const float4*>(h1 + (size_t)n0 * 512);
    float4* hdst = reinterpret_cast<float4*>(hs);
    for (int i = t; i < 512; i += 256) hdst[i] = hsrc[i];
    __syncthreads();
    int r = t >> 6, j = t & 63;
    const float* W = (j < 32) ? (Wl + j) : (Wr + (j - 32));
    float acc = 0.f;
#pragma unroll 8
    for (int k = 0; k < 512; ++k)
        acc += hs[r * 512 + k] * W[(size_t)k * 32];
    xw2[(size_t)(n0 + r) * 64 + j] = acc;
}

// 32 lanes per edge
__global__ __launch_bounds__(256) void k_edge2(const int* __restrict__ ssrc,
        const int* __restrict__ sdst, const float* __restrict__ xw2,
        const float* __restrict__ att2, float* __restrict__ alpha2) {
    int t = threadIdx.x;
    int sub = t >> 5, lane = t & 31;
    int pos = blockIdx.x * 8 + sub;
    if (pos >= ET) return;
    int s = ssrc[pos], d = sdst[pos];
    float a = xw2[(size_t)s * 64 + lane] + xw2[(size_t)d * 64 + 32 + lane];
    a = (a > 0.f) ? a : NEG_SLOPE * a;
    float p = a * att2[lane];
    for (int o = 16; o; o >>= 1) p += __shfl_xor(p, o);
    if (lane == 0) alpha2[pos] = p;
}

// one wave per node: softmax-agg (lanes 0-31 = channels) + log_softmax
__global__ __launch_bounds__(64) void k_node2(const int* __restrict__ offs,
        const int* __restrict__ ssrc, const float* __restrict__ alpha2,
        const float* __restrict__ xw2, const float* __restrict__ b2,
        float* __restrict__ out) {
    int n = blockIdx.x;
    int lane = threadIdx.x;
    int beg = offs[n], dcnt = offs[n + 1] - beg;
    float m = -1e30f;
    for (int i = lane; i < dcnt; i += 64) m = fmaxf(m, alpha2[beg + i]);
    for (int o = 32; o; o >>= 1) m = fmaxf(m, __shfl_down(m, o));
    m = __shfl(m, 0);
    float s = 0.f;
    for (int i = lane; i < dcnt; i += 64) s += __expf(alpha2[beg + i] - m);
    for (int o = 32; o; o >>= 1) s += __shfl_down(s, o);
    s = __shfl(s, 0);
    float inv = 1.f / (s + 1e-16f);
    if (lane < 32) {
        float acc = 0.f;
        for (int i = 0; i < dcnt; ++i) {
            int pos = beg + i;
            float w = __expf(alpha2[pos] - m);
            int sn = ssrc[pos];
            acc += w * xw2[(size_t)sn * 64 + lane];
        }
        float v = acc * inv + b2[lane];
        // log_softmax over the 32 channels (lanes 0..31)
        float mx = v;
        for (int o = 16; o; o >>= 1) mx = fmaxf(mx, __shfl_xor(mx, o));
        float se = __expf(v - mx);
        for (int o = 16; o; o >>= 1) se += __shfl_xor(se, o);
        float r = (v - mx) - __logf(se);
        out[(size_t)n * 32 + lane] = r;
    }
}

// ---------------- launch ----------------

extern "C" void kernel_launch(void* const* d_in, const int* in_sizes, int n_in,
                              void* d_out, int out_size, void* d_ws, size_t ws_size,
                              hipStream_t stream) {
    (void)in_sizes; (void)n_in; (void)out_size; (void)ws_size;
    const float* x    = (const float*)d_in[0];
    const int*   ei   = (const int*)d_in[1];
    const float* W1l  = (const float*)d_in[2];
    const float* W1r  = (const float*)d_in[3];
    const float* att1 = (const float*)d_in[4];
    const float* b1   = (const float*)d_in[5];
    const float* W2l  = (const float*)d_in[6];
    const float* W2r  = (const float*)d_in[7];
    const float* att2 = (const float*)d_in[8];
    const float* b2   = (const float*)d_in[9];
    float* outp = (float*)d_out;

    char* ws = (char*)d_ws;
    size_t o = 0;
    auto alloc = [&](size_t bytes) {
        char* p = ws + o;
        o = (o + bytes + 255) & ~(size_t)255;
        return p;
    };
    float* xl1    = (float*)alloc((size_t)N_NODES * 512 * 4);
    float* xr1    = (float*)alloc((size_t)N_NODES * 512 * 4);
    float* h1     = (float*)alloc((size_t)N_NODES * 512 * 4);
    float* xw2    = (float*)alloc((size_t)N_NODES * 64 * 4);
    float* alpha1 = (float*)alloc((size_t)ET * 8 * 4);
    float* alpha2 = (float*)alloc((size_t)ET * 4);
    int*   deg    = (int*)alloc((size_t)N_NODES * 4);
    int*   cursor = (int*)alloc((size_t)N_NODES * 4);
    int*   offs   = (int*)alloc((size_t)(N_NODES + 1) * 4);
    int*   ssrc   = (int*)alloc((size_t)ET * 4);
    int*   sdst   = (int*)alloc((size_t)ET * 4);
    // total ~79 MB of d_ws

    hipMemsetAsync(deg, 0, (size_t)N_NODES * 4, stream);
    hipMemsetAsync(cursor, 0, (size_t)N_NODES * 4, stream);

    k_gemm1  <<<N_NODES / 16,       256, 0, stream>>>(x, W1l, W1r, xl1, xr1);
    k_count  <<<(ET + 255) / 256,   256, 0, stream>>>(ei, deg);
    k_scan   <<<1,                 1024, 0, stream>>>(deg, offs);
    k_scatter<<<(ET + 255) / 256,   256, 0, stream>>>(ei, offs, cursor, ssrc, sdst);
    k_edge1  <<<(ET + 3) / 4,       256, 0, stream>>>(ssrc, sdst, xl1, xr1, att1, alpha1);
    k_node1  <<<N_NODES,            512, 0, stream>>>(offs, ssrc, alpha1, xl1, b1, h1);
    k_gemm2  <<<N_NODES / 4,        256, 0, stream>>>(h1, W2l, W2r, xw2);
    k_edge2  <<<(ET + 7) / 8,       256, 0, stream>>>(ssrc, sdst, xw2, att2, alpha2);
    k_node2  <<<N_NODES,             64, 0, stream>>>(offs, ssrc, alpha2, xw2, b2, outp);
}

// Round 3
// 517.398 us; speedup vs baseline: 1.1986x; 1.1986x over previous
//
#include <hip/hip_runtime.h>
#include <hip/hip_bf16.h>

// GATv2 x2 on MI355X — fp32, fused attention. Pipeline:
//  1. CSR build: count deg(dst) -> scan -> scatter edge srcs sorted by dst
//  2. gemm1: xl1/xr1 = x @ W1l / W1r              (fp32, [N,512] each)
//  3. node1f: per-dst ONLINE softmax-agg fused with alpha computation
//             (wave h = head h; gather xl1[s] once per edge) + bias + elu -> h1
//  4. gemm2: xw2 = h1 @ [W2l | W2r]               ([N,64]: 0-31 xl2, 32-63 xr2)
//  5. node2f: online softmax-agg (2 edges/wave in 32-lane halves) + bias
//             + log_softmax -> out

constexpr int N_NODES = 10000;
constexpr int N_EDGES = 320000;
constexpr int ET      = N_EDGES + N_NODES;   // 330000 incl. self loops
constexpr float NEG_SLOPE = 0.2f;

// ---------------- CSR build ----------------

__global__ void k_count(const int* __restrict__ ei, int* __restrict__ deg) {
    int e = blockIdx.x * 256 + threadIdx.x;
    if (e >= ET) return;
    int d = (e < N_EDGES) ? ei[N_EDGES + e] : (e - N_EDGES);
    atomicAdd(&deg[d], 1);
}

__global__ __launch_bounds__(1024) void k_scan(const int* __restrict__ deg,
                                               int* __restrict__ offs) {
    __shared__ int part[1024];
    const int CH = 10;                       // ceil(10000/1024)
    int t = threadIdx.x;
    int base = t * CH;
    int loc[CH];
    int s = 0;
    for (int i = 0; i < CH; ++i) {
        int idx = base + i;
        int v = (idx < N_NODES) ? deg[idx] : 0;
        loc[i] = s; s += v;
    }
    part[t] = s;
    __syncthreads();
    for (int o = 1; o < 1024; o <<= 1) {
        int add = (t >= o) ? part[t - o] : 0;
        __syncthreads();
        part[t] += add;
        __syncthreads();
    }
    int excl = part[t] - s;
    for (int i = 0; i < CH; ++i) {
        int idx = base + i;
        if (idx < N_NODES) offs[idx] = excl + loc[i];
    }
    if (t == 1023) offs[N_NODES] = part[1023];
}

__global__ void k_scatter(const int* __restrict__ ei, const int* __restrict__ offs,
                          int* __restrict__ cursor, int* __restrict__ ssrc) {
    int e = blockIdx.x * 256 + threadIdx.x;
    if (e >= ET) return;
    int s, d;
    if (e < N_EDGES) { s = ei[e]; d = ei[N_EDGES + e]; }
    else             { s = d = e - N_EDGES; }
    int pos = offs[d] + atomicAdd(&cursor[d], 1);
    ssrc[pos] = s;
}

// ---------------- layer 1 ----------------

// 16 rows x 1024 cols (W1l||W1r fused) per block, 256 threads, 4 cols/thread.
// k-unrolled x4: ds_read_b128 for x, 4x float4 W loads per iter.
__global__ __launch_bounds__(256) void k_gemm1(const float* __restrict__ x,
        const float* __restrict__ Wl, const float* __restrict__ Wr,
        float* __restrict__ xl1, float* __restrict__ xr1) {
    __shared__ float xs[16 * 256];
    int t = threadIdx.x;
    int row0 = blockIdx.x * 16;
    const float4* xsrc = reinterpret_cast<const float4*>(x + (size_t)row0 * 256);
    float4* xdst = reinterpret_cast<float4*>(xs);
    for (int i = t; i < 16 * 64; i += 256) xdst[i] = xsrc[i];
    __syncthreads();
    int cb = t * 4;
    const float* W = (cb < 512) ? (Wl + cb) : (Wr + (cb - 512));
    float acc[16][4];
#pragma unroll
    for (int r = 0; r < 16; ++r)
        for (int j = 0; j < 4; ++j) acc[r][j] = 0.f;
    for (int k = 0; k < 256; k += 4) {
        float4 w0 = *reinterpret_cast<const float4*>(W + (size_t)(k + 0) * 512);
        float4 w1 = *reinterpret_cast<const float4*>(W + (size_t)(k + 1) * 512);
        float4 w2 = *reinterpret_cast<const float4*>(W + (size_t)(k + 2) * 512);
        float4 w3 = *reinterpret_cast<const float4*>(W + (size_t)(k + 3) * 512);
#pragma unroll
        for (int r = 0; r < 16; ++r) {
            float4 a = *reinterpret_cast<const float4*>(&xs[r * 256 + k]);
            acc[r][0] += a.x * w0.x + a.y * w1.x + a.z * w2.x + a.w * w3.x;
            acc[r][1] += a.x * w0.y + a.y * w1.y + a.z * w2.y + a.w * w3.y;
            acc[r][2] += a.x * w0.z + a.y * w1.z + a.z * w2.z + a.w * w3.z;
            acc[r][3] += a.x * w0.w + a.y * w1.w + a.z * w2.w + a.w * w3.w;
        }
    }
    float* outp = (cb < 512) ? (xl1 + cb) : (xr1 + (cb - 512));
    for (int r = 0; r < 16; ++r) {
        float4 v = make_float4(acc[r][0], acc[r][1], acc[r][2], acc[r][3]);
        *reinterpret_cast<float4*>(outp + (size_t)(row0 + r) * 512) = v;
    }
}

// Fused edge+node layer 1: one block (512 thr = 8 waves) per node.
// Wave h owns head h; lane = channel. Online softmax over incoming edges.
__global__ __launch_bounds__(512) void k_node1f(const int* __restrict__ offs,
        const int* __restrict__ ssrc, const float* __restrict__ xl1,
        const float* __restrict__ xr1, const float* __restrict__ att1,
        const float* __restrict__ b1, float* __restrict__ h1) {
    int n = blockIdx.x;
    int t = threadIdx.x;                 // t = h*64 + c
    int beg = offs[n], dcnt = offs[n + 1] - beg;
    float xr = xr1[(size_t)n * 512 + t];
    float at = att1[t];
    float m = -1e30f, l = 0.f, acc = 0.f;
    // software-pipelined gather of xl rows
    float xl = xl1[(size_t)ssrc[beg] * 512 + t];
    for (int i = 0; i < dcnt; ++i) {
        float xl_next = 0.f;
        if (i + 1 < dcnt)
            xl_next = xl1[(size_t)ssrc[beg + i + 1] * 512 + t];
        float a = xl + xr;
        a = (a > 0.f) ? a : NEG_SLOPE * a;
        float p = a * at;
#pragma unroll
        for (int o = 32; o; o >>= 1) p += __shfl_xor(p, o);
        // p is wave-uniform -> uniform branch; common path = 1 exp
        if (p <= m) {
            float w = __expf(p - m);
            l += w;
            acc += w * xl;
        } else {
            float sc = __expf(m - p);    // m=-1e30 first iter -> underflows to 0
            l = l * sc + 1.f;
            acc = acc * sc + xl;
            m = p;
        }
        xl = xl_next;
    }
    float v = acc / (l + 1e-16f) + b1[t];
    v = (v > 0.f) ? v : expm1f(v);       // elu
    h1[(size_t)n * 512 + t] = v;
}

// ---------------- layer 2 ----------------

// 4 rows x 64 cols (W2l||W2r fused) per block, 256 threads, k-unroll x4.
__global__ __launch_bounds__(256) void k_gemm2(const float* __restrict__ h1,
        const float* __restrict__ Wl, const float* __restrict__ Wr,
        float* __restrict__ xw2) {
    __shared__ float hs[4 * 512];
    int t = threadIdx.x;
    int n0 = blockIdx.x * 4;
    const float4* hsrc = reinterpret_cast<const float4*>(h1 + (size_t)n0 * 512);
    float4* hdst = reinterpret_cast<float4*>(hs);
    for (int i = t; i < 512; i += 256) hdst[i] = hsrc[i];
    __syncthreads();
    int r = t >> 6, j = t & 63;
    const float* W = (j < 32) ? (Wl + j) : (Wr + (j - 32));
    float acc = 0.f;
    for (int k = 0; k < 512; k += 4) {
        float4 a = *reinterpret_cast<const float4*>(&hs[r * 512 + k]);
        acc += a.x * W[(size_t)(k + 0) * 32] + a.y * W[(size_t)(k + 1) * 32]
             + a.z * W[(size_t)(k + 2) * 32] + a.w * W[(size_t)(k + 3) * 32];
    }
    xw2[(size_t)(n0 + r) * 64 + j] = acc;
}

// Fused edge+node layer 2 + log_softmax: one wave per node (4 nodes / 256-blk).
// Two edges processed per wave in 32-lane halves with independent online
// state, merged at the end.
__global__ __launch_bounds__(256) void k_node2f(const int* __restrict__ offs,
        const int* __restrict__ ssrc, const float* __restrict__ xw2,
        const float* __restrict__ att2, const float* __restrict__ b2,
        float* __restrict__ out) {
    int t = threadIdx.x;
    int n = blockIdx.x * 4 + (t >> 6);
    int lane = t & 63;
    int half = lane >> 5;                // which edge of the pair
    int c = lane & 31;                   // channel
    int beg = offs[n], dcnt = offs[n + 1] - beg;
    float xr = xw2[(size_t)n * 64 + 32 + c];
    float at = att2[c];
    float m = -1e30f, l = 0.f, acc = 0.f;
    for (int base = 0; base < dcnt; base += 2) {
        int i = base + half;
        bool active = (i < dcnt);
        int s = active ? ssrc[beg + i] : 0;
        float xl = xw2[(size_t)s * 64 + c];
        float a = xl + xr;
        a = (a > 0.f) ? a : NEG_SLOPE * a;
        float p = a * at;
#pragma unroll
        for (int o = 16; o; o >>= 1) p += __shfl_xor(p, o);  // within 32-half
        p = active ? p : -1e30f;
        // branchless online update (inactive: mn=m, w=0 -> state unchanged)
        float mn = fmaxf(m, p);
        float sc = __expf(m - mn);
        float w  = __expf(p - mn);
        l   = l * sc + w;
        acc = acc * sc + w * xl;
        m = mn;
    }
    // merge the two halves
    float m2   = __shfl_xor(m, 32);
    float l2   = __shfl_xor(l, 32);
    float acc2 = __shfl_xor(acc, 32);
    float M  = fmaxf(m, m2);
    float w1 = __expf(m - M), w2 = __expf(m2 - M);
    l   = l * w1 + l2 * w2;
    acc = acc * w1 + acc2 * w2;
    float v = acc / (l + 1e-16f) + b2[c];
    // log_softmax over 32 channels (identical in both halves)
    float mx = v;
#pragma unroll
    for (int o = 16; o; o >>= 1) mx = fmaxf(mx, __shfl_xor(mx, o));
    float se = __expf(v - mx);
#pragma unroll
    for (int o = 16; o; o >>= 1) se += __shfl_xor(se, o);
    float r = (v - mx) - __logf(se);
    if (half == 0) out[(size_t)n * 32 + c] = r;
}

// ---------------- launch ----------------

extern "C" void kernel_launch(void* const* d_in, const int* in_sizes, int n_in,
                              void* d_out, int out_size, void* d_ws, size_t ws_size,
                              hipStream_t stream) {
    (void)in_sizes; (void)n_in; (void)out_size; (void)ws_size;
    const float* x    = (const float*)d_in[0];
    const int*   ei   = (const int*)d_in[1];
    const float* W1l  = (const float*)d_in[2];
    const float* W1r  = (const float*)d_in[3];
    const float* att1 = (const float*)d_in[4];
    const float* b1   = (const float*)d_in[5];
    const float* W2l  = (const float*)d_in[6];
    const float* W2r  = (const float*)d_in[7];
    const float* att2 = (const float*)d_in[8];
    const float* b2   = (const float*)d_in[9];
    float* outp = (float*)d_out;

    char* ws = (char*)d_ws;
    size_t o = 0;
    auto alloc = [&](size_t bytes) {
        char* p = ws + o;
        o = (o + bytes + 255) & ~(size_t)255;
        return p;
    };
    float* xl1    = (float*)alloc((size_t)N_NODES * 512 * 4);
    float* xr1    = (float*)alloc((size_t)N_NODES * 512 * 4);
    float* h1     = (float*)alloc((size_t)N_NODES * 512 * 4);
    float* xw2    = (float*)alloc((size_t)N_NODES * 64 * 4);
    int*   deg    = (int*)alloc((size_t)N_NODES * 4);
    int*   cursor = (int*)alloc((size_t)N_NODES * 4);
    int*   offs   = (int*)alloc((size_t)(N_NODES + 1) * 4);
    int*   ssrc   = (int*)alloc((size_t)ET * 4);
    // total ~65 MB of d_ws

    hipMemsetAsync(deg, 0, (size_t)N_NODES * 4, stream);
    hipMemsetAsync(cursor, 0, (size_t)N_NODES * 4, stream);

    k_count  <<<(ET + 255) / 256,   256, 0, stream>>>(ei, deg);
    k_scan   <<<1,                 1024, 0, stream>>>(deg, offs);
    k_scatter<<<(ET + 255) / 256,   256, 0, stream>>>(ei, offs, cursor, ssrc);
    k_gemm1  <<<N_NODES / 16,       256, 0, stream>>>(x, W1l, W1r, xl1, xr1);
    k_node1f <<<N_NODES,            512, 0, stream>>>(offs, ssrc, xl1, xr1, att1, b1, h1);
    k_gemm2  <<<N_NODES / 4,        256, 0, stream>>>(h1, W2l, W2r, xw2);
    k_node2f <<<N_NODES / 4,        256, 0, stream>>>(offs, ssrc, xw2, att2, b2, outp);
}

// Round 4
// 494.873 us; speedup vs baseline: 1.2531x; 1.0455x over previous
//
#include <hip/hip_runtime.h>
#include <hip/hip_bf16.h>

// GATv2 x2 on MI355X — fp32, fused attention, chunked-ILP online softmax.
//  1. CSR build: count deg(dst) -> scan -> scatter edge srcs sorted by dst
//  2. gemm1: xl1/xr1 = x @ W1l / W1r              (fp32, [N,512] each)
//  3. node1f: per-dst online softmax-agg, 8 edges in flight (chunked),
//             ssrc staged in LDS, + bias + elu -> h1
//  4. gemm2: xw2 = h1 @ [W2l | W2r]               ([N,64]: 0-31 xl2, 32-63 xr2)
//  5. node2f: online softmax-agg (2x 32-lane halves x 4-chunk = 8 edges in
//             flight) + bias + log_softmax -> out

constexpr int N_NODES = 10000;
constexpr int N_EDGES = 320000;
constexpr int ET      = N_EDGES + N_NODES;   // 330000 incl. self loops
constexpr float NEG_SLOPE = 0.2f;

// ---------------- CSR build ----------------

__global__ void k_count(const int* __restrict__ ei, int* __restrict__ deg) {
    int e = blockIdx.x * 256 + threadIdx.x;
    if (e >= ET) return;
    int d = (e < N_EDGES) ? ei[N_EDGES + e] : (e - N_EDGES);
    atomicAdd(&deg[d], 1);
}

__global__ __launch_bounds__(1024) void k_scan(const int* __restrict__ deg,
                                               int* __restrict__ offs) {
    __shared__ int part[1024];
    const int CH = 10;                       // ceil(10000/1024)
    int t = threadIdx.x;
    int base = t * CH;
    int loc[CH];
    int s = 0;
    for (int i = 0; i < CH; ++i) {
        int idx = base + i;
        int v = (idx < N_NODES) ? deg[idx] : 0;
        loc[i] = s; s += v;
    }
    part[t] = s;
    __syncthreads();
    for (int o = 1; o < 1024; o <<= 1) {
        int add = (t >= o) ? part[t - o] : 0;
        __syncthreads();
        part[t] += add;
        __syncthreads();
    }
    int excl = part[t] - s;
    for (int i = 0; i < CH; ++i) {
        int idx = base + i;
        if (idx < N_NODES) offs[idx] = excl + loc[i];
    }
    if (t == 1023) offs[N_NODES] = part[1023];
}

__global__ void k_scatter(const int* __restrict__ ei, const int* __restrict__ offs,
                          int* __restrict__ cursor, int* __restrict__ ssrc) {
    int e = blockIdx.x * 256 + threadIdx.x;
    if (e >= ET) return;
    int s, d;
    if (e < N_EDGES) { s = ei[e]; d = ei[N_EDGES + e]; }
    else             { s = d = e - N_EDGES; }
    int pos = offs[d] + atomicAdd(&cursor[d], 1);
    ssrc[pos] = s;
}

// ---------------- layer 1 ----------------

// 16 rows x 1024 cols (W1l||W1r fused) per block, 256 threads, 4 cols/thread.
__global__ __launch_bounds__(256) void k_gemm1(const float* __restrict__ x,
        const float* __restrict__ Wl, const float* __restrict__ Wr,
        float* __restrict__ xl1, float* __restrict__ xr1) {
    __shared__ float xs[16 * 256];
    int t = threadIdx.x;
    int row0 = blockIdx.x * 16;
    const float4* xsrc = reinterpret_cast<const float4*>(x + (size_t)row0 * 256);
    float4* xdst = reinterpret_cast<float4*>(xs);
    for (int i = t; i < 16 * 64; i += 256) xdst[i] = xsrc[i];
    __syncthreads();
    int cb = t * 4;
    const float* W = (cb < 512) ? (Wl + cb) : (Wr + (cb - 512));
    float acc[16][4];
#pragma unroll
    for (int r = 0; r < 16; ++r)
        for (int j = 0; j < 4; ++j) acc[r][j] = 0.f;
    for (int k = 0; k < 256; k += 4) {
        float4 w0 = *reinterpret_cast<const float4*>(W + (size_t)(k + 0) * 512);
        float4 w1 = *reinterpret_cast<const float4*>(W + (size_t)(k + 1) * 512);
        float4 w2 = *reinterpret_cast<const float4*>(W + (size_t)(k + 2) * 512);
        float4 w3 = *reinterpret_cast<const float4*>(W + (size_t)(k + 3) * 512);
#pragma unroll
        for (int r = 0; r < 16; ++r) {
            float4 a = *reinterpret_cast<const float4*>(&xs[r * 256 + k]);
            acc[r][0] += a.x * w0.x + a.y * w1.x + a.z * w2.x + a.w * w3.x;
            acc[r][1] += a.x * w0.y + a.y * w1.y + a.z * w2.y + a.w * w3.y;
            acc[r][2] += a.x * w0.z + a.y * w1.z + a.z * w2.z + a.w * w3.z;
            acc[r][3] += a.x * w0.w + a.y * w1.w + a.z * w2.w + a.w * w3.w;
        }
    }
    float* outp = (cb < 512) ? (xl1 + cb) : (xr1 + (cb - 512));
    for (int r = 0; r < 16; ++r) {
        float4 v = make_float4(acc[r][0], acc[r][1], acc[r][2], acc[r][3]);
        *reinterpret_cast<float4*>(outp + (size_t)(row0 + r) * 512) = v;
    }
}

// Fused edge+node layer 1: one block (512 thr = 8 waves) per node.
// Wave h owns head h; lane = channel. Online softmax, 8 edges in flight.
__global__ __launch_bounds__(512) void k_node1f(const int* __restrict__ offs,
        const int* __restrict__ ssrc, const float* __restrict__ xl1,
        const float* __restrict__ xr1, const float* __restrict__ att1,
        const float* __restrict__ b1, float* __restrict__ h1) {
    constexpr int C = 8;
    __shared__ int slds[256];
    int n = blockIdx.x;
    int t = threadIdx.x;                 // t = h*64 + c
    int beg = offs[n], dcnt = offs[n + 1] - beg;
    int cap = (dcnt < 256) ? dcnt : 256;
    for (int i = t; i < cap; i += 512) slds[i] = ssrc[beg + i];
    __syncthreads();
    float xr = xr1[(size_t)n * 512 + t];
    float at = att1[t];
    float m = -1e30f, l = 0.f, acc = 0.f;
    float xl_cur[C];
#pragma unroll
    for (int j = 0; j < C; ++j) {
        if (j < dcnt) {
            int s = (j < 256) ? slds[j] : ssrc[beg + j];
            xl_cur[j] = xl1[(size_t)s * 512 + t];
        } else xl_cur[j] = 0.f;
    }
    for (int base = 0; base < dcnt; base += C) {
        float xl_nxt[C];
#pragma unroll
        for (int j = 0; j < C; ++j) {
            int i = base + C + j;
            if (i < dcnt) {
                int s = (i < 256) ? slds[i] : ssrc[beg + i];
                xl_nxt[j] = xl1[(size_t)s * 512 + t];
            } else xl_nxt[j] = 0.f;
        }
        float p[C];
#pragma unroll
        for (int j = 0; j < C; ++j) {
            float a = xl_cur[j] + xr;
            a = (a > 0.f) ? a : NEG_SLOPE * a;
            p[j] = a * at;
        }
#pragma unroll
        for (int o = 32; o; o >>= 1)
#pragma unroll
            for (int j = 0; j < C; ++j)
                p[j] += __shfl_xor(p[j], o);
        float pm = -1e30f;
#pragma unroll
        for (int j = 0; j < C; ++j) {
            if (base + j >= dcnt) p[j] = -1e30f;
            pm = fmaxf(pm, p[j]);
        }
        float mn = fmaxf(m, pm);
        float sc = __expf(m - mn);       // first chunk: exp(-inf) = 0
        l *= sc; acc *= sc;
#pragma unroll
        for (int j = 0; j < C; ++j) {
            float w = __expf(p[j] - mn); // inactive: exp(-inf) = 0
            l += w;
            acc += w * xl_cur[j];
        }
        m = mn;
#pragma unroll
        for (int j = 0; j < C; ++j) xl_cur[j] = xl_nxt[j];
    }
    float v = acc / (l + 1e-16f) + b1[t];
    v = (v > 0.f) ? v : expm1f(v);       // elu
    h1[(size_t)n * 512 + t] = v;
}

// ---------------- layer 2 ----------------

// 4 rows x 64 cols (W2l||W2r fused) per block, 256 threads, k-unroll x4.
__global__ __launch_bounds__(256) void k_gemm2(const float* __restrict__ h1,
        const float* __restrict__ Wl, const float* __restrict__ Wr,
        float* __restrict__ xw2) {
    __shared__ float hs[4 * 512];
    int t = threadIdx.x;
    int n0 = blockIdx.x * 4;
    const float4* hsrc = reinterpret_cast<const float4*>(h1 + (size_t)n0 * 512);
    float4* hdst = reinterpret_cast<float4*>(hs);
    for (int i = t; i < 512; i += 256) hdst[i] = hsrc[i];
    __syncthreads();
    int r = t >> 6, j = t & 63;
    const float* W = (j < 32) ? (Wl + j) : (Wr + (j - 32));
    float acc = 0.f;
    for (int k = 0; k < 512; k += 4) {
        float4 a = *reinterpret_cast<const float4*>(&hs[r * 512 + k]);
        acc += a.x * W[(size_t)(k + 0) * 32] + a.y * W[(size_t)(k + 1) * 32]
             + a.z * W[(size_t)(k + 2) * 32] + a.w * W[(size_t)(k + 3) * 32];
    }
    xw2[(size_t)(n0 + r) * 64 + j] = acc;
}

// Fused edge+node layer 2 + log_softmax: one wave per node (4 nodes / 256-blk).
// 2 halves x 4-chunk = 8 edges in flight per wave.
__global__ __launch_bounds__(256) void k_node2f(const int* __restrict__ offs,
        const int* __restrict__ ssrc, const float* __restrict__ xw2,
        const float* __restrict__ att2, const float* __restrict__ b2,
        float* __restrict__ out) {
    constexpr int C = 4;
    __shared__ int slds[4 * 128];
    int t = threadIdx.x;
    int w = t >> 6;
    int n = blockIdx.x * 4 + w;
    int lane = t & 63;
    int half = lane >> 5;                // which edge of each pair
    int c = lane & 31;                   // channel
    int beg = offs[n], dcnt = offs[n + 1] - beg;
    int cap = (dcnt < 128) ? dcnt : 128;
    for (int i = lane; i < cap; i += 64) slds[w * 128 + i] = ssrc[beg + i];
    __syncthreads();
    float xr = xw2[(size_t)n * 64 + 32 + c];
    float at = att2[c];
    float m = -1e30f, l = 0.f, acc = 0.f;
    for (int base = 0; base < dcnt; base += 2 * C) {
        float p[C], xl[C];
#pragma unroll
        for (int j = 0; j < C; ++j) {
            int i = base + 2 * j + half;
            int s = (i < dcnt) ? ((i < 128) ? slds[w * 128 + i] : ssrc[beg + i]) : 0;
            xl[j] = xw2[(size_t)s * 64 + c];
        }
#pragma unroll
        for (int j = 0; j < C; ++j) {
            float a = xl[j] + xr;
            a = (a > 0.f) ? a : NEG_SLOPE * a;
            p[j] = a * at;
        }
#pragma unroll
        for (int o = 16; o; o >>= 1)
#pragma unroll
            for (int j = 0; j < C; ++j)
                p[j] += __shfl_xor(p[j], o);     // within 32-half
        float pm = -1e30f;
#pragma unroll
        for (int j = 0; j < C; ++j) {
            if (base + 2 * j + half >= dcnt) p[j] = -1e30f;
            pm = fmaxf(pm, p[j]);
        }
        float mn = fmaxf(m, pm);
        float sc = __expf(m - mn);
        l *= sc; acc *= sc;
#pragma unroll
        for (int j = 0; j < C; ++j) {
            float wj = __expf(p[j] - mn);
            l += wj;
            acc += wj * xl[j];
        }
        m = mn;
    }
    // merge the two halves
    float m2   = __shfl_xor(m, 32);
    float l2   = __shfl_xor(l, 32);
    float acc2 = __shfl_xor(acc, 32);
    float M  = fmaxf(m, m2);
    float w1 = __expf(m - M), w2 = __expf(m2 - M);
    l   = l * w1 + l2 * w2;
    acc = acc * w1 + acc2 * w2;
    float v = acc / (l + 1e-16f) + b2[c];
    // log_softmax over 32 channels (identical in both halves)
    float mx = v;
#pragma unroll
    for (int o = 16; o; o >>= 1) mx = fmaxf(mx, __shfl_xor(mx, o));
    float se = __expf(v - mx);
#pragma unroll
    for (int o = 16; o; o >>= 1) se += __shfl_xor(se, o);
    float r = (v - mx) - __logf(se);
    if (half == 0) out[(size_t)n * 32 + c] = r;
}

// ---------------- launch ----------------

extern "C" void kernel_launch(void* const* d_in, const int* in_sizes, int n_in,
                              void* d_out, int out_size, void* d_ws, size_t ws_size,
                              hipStream_t stream) {
    (void)in_sizes; (void)n_in; (void)out_size; (void)ws_size;
    const float* x    = (const float*)d_in[0];
    const int*   ei   = (const int*)d_in[1];
    const float* W1l  = (const float*)d_in[2];
    const float* W1r  = (const float*)d_in[3];
    const float* att1 = (const float*)d_in[4];
    const float* b1   = (const float*)d_in[5];
    const float* W2l  = (const float*)d_in[6];
    const float* W2r  = (const float*)d_in[7];
    const float* att2 = (const float*)d_in[8];
    const float* b2   = (const float*)d_in[9];
    float* outp = (float*)d_out;

    char* ws = (char*)d_ws;
    size_t o = 0;
    auto alloc = [&](size_t bytes) {
        char* p = ws + o;
        o = (o + bytes + 255) & ~(size_t)255;
        return p;
    };
    float* xl1    = (float*)alloc((size_t)N_NODES * 512 * 4);
    float* xr1    = (float*)alloc((size_t)N_NODES * 512 * 4);
    float* h1     = (float*)alloc((size_t)N_NODES * 512 * 4);
    float* xw2    = (float*)alloc((size_t)N_NODES * 64 * 4);
    int*   deg    = (int*)alloc((size_t)N_NODES * 4);
    int*   cursor = (int*)alloc((size_t)N_NODES * 4);
    int*   offs   = (int*)alloc((size_t)(N_NODES + 1) * 4);
    int*   ssrc   = (int*)alloc((size_t)ET * 4);

    hipMemsetAsync(deg, 0, (size_t)N_NODES * 4, stream);
    hipMemsetAsync(cursor, 0, (size_t)N_NODES * 4, stream);

    k_count  <<<(ET + 255) / 256,   256, 0, stream>>>(ei, deg);
    k_scan   <<<1,                 1024, 0, stream>>>(deg, offs);
    k_scatter<<<(ET + 255) / 256,   256, 0, stream>>>(ei, offs, cursor, ssrc);
    k_gemm1  <<<N_NODES / 16,       256, 0, stream>>>(x, W1l, W1r, xl1, xr1);
    k_node1f <<<N_NODES,            512, 0, stream>>>(offs, ssrc, xl1, xr1, att1, b1, h1);
    k_gemm2  <<<N_NODES / 4,        256, 0, stream>>>(h1, W2l, W2r, xw2);
    k_node2f <<<N_NODES / 4,        256, 0, stream>>>(offs, ssrc, xw2, att2, b2, outp);
}

// Round 5
// 442.172 us; speedup vs baseline: 1.4025x; 1.1192x over previous
//
#include <hip/hip_runtime.h>
#include <hip/hip_bf16.h>

// GATv2 x2 on MI355X — fp32, fused attention, phase-split reduction.
//  node kernels: per 8-edge chunk, phase 1 computes the 8 alphas with
//  lane=(edge, ch-group) layout (3 xor-shuffles over 8 lanes instead of a
//  64-lane butterfly per edge), phase 2 aggregates with lane=channel using
//  wave-uniform weights (rows are L1-hot from phase 1).

constexpr int N_NODES = 10000;
constexpr int N_EDGES = 320000;
constexpr int ET      = N_EDGES + N_NODES;   // 330000 incl. self loops
constexpr float NEG_SLOPE = 0.2f;
constexpr int MAXD1 = 384;                   // LDS ssrc cache per node (layer1)
constexpr int MAXD2 = 160;                   // per node (layer2, 4 nodes/block)

__device__ __forceinline__ float lrelu(float a) {
    return (a > 0.f) ? a : NEG_SLOPE * a;
}

// ---------------- CSR build ----------------

__global__ void k_count(const int* __restrict__ ei, int* __restrict__ deg) {
    int e = blockIdx.x * 256 + threadIdx.x;
    if (e >= ET) return;
    int d = (e < N_EDGES) ? ei[N_EDGES + e] : (e - N_EDGES);
    atomicAdd(&deg[d], 1);
}

__global__ __launch_bounds__(1024) void k_scan(const int* __restrict__ deg,
                                               int* __restrict__ offs) {
    __shared__ int part[1024];
    const int CH = 10;                       // ceil(10000/1024)
    int t = threadIdx.x;
    int base = t * CH;
    int loc[CH];
    int s = 0;
    for (int i = 0; i < CH; ++i) {
        int idx = base + i;
        int v = (idx < N_NODES) ? deg[idx] : 0;
        loc[i] = s; s += v;
    }
    part[t] = s;
    __syncthreads();
    for (int o = 1; o < 1024; o <<= 1) {
        int add = (t >= o) ? part[t - o] : 0;
        __syncthreads();
        part[t] += add;
        __syncthreads();
    }
    int excl = part[t] - s;
    for (int i = 0; i < CH; ++i) {
        int idx = base + i;
        if (idx < N_NODES) offs[idx] = excl + loc[i];
    }
    if (t == 1023) offs[N_NODES] = part[1023];
}

__global__ void k_scatter(const int* __restrict__ ei, const int* __restrict__ offs,
                          int* __restrict__ cursor, int* __restrict__ ssrc) {
    int e = blockIdx.x * 256 + threadIdx.x;
    if (e >= ET) return;
    int s, d;
    if (e < N_EDGES) { s = ei[e]; d = ei[N_EDGES + e]; }
    else             { s = d = e - N_EDGES; }
    int pos = offs[d] + atomicAdd(&cursor[d], 1);
    ssrc[pos] = s;
}

// ---------------- layer 1 ----------------

// 16 rows x 1024 cols (W1l||W1r fused) per block, 256 threads, 4 cols/thread.
__global__ __launch_bounds__(256) void k_gemm1(const float* __restrict__ x,
        const float* __restrict__ Wl, const float* __restrict__ Wr,
        float* __restrict__ xl1, float* __restrict__ xr1) {
    __shared__ float xs[16 * 256];
    int t = threadIdx.x;
    int row0 = blockIdx.x * 16;
    const float4* xsrc = reinterpret_cast<const float4*>(x + (size_t)row0 * 256);
    float4* xdst = reinterpret_cast<float4*>(xs);
    for (int i = t; i < 16 * 64; i += 256) xdst[i] = xsrc[i];
    __syncthreads();
    int cb = t * 4;
    const float* W = (cb < 512) ? (Wl + cb) : (Wr + (cb - 512));
    float acc[16][4];
#pragma unroll
    for (int r = 0; r < 16; ++r)
        for (int j = 0; j < 4; ++j) acc[r][j] = 0.f;
    for (int k = 0; k < 256; k += 4) {
        float4 w0 = *reinterpret_cast<const float4*>(W + (size_t)(k + 0) * 512);
        float4 w1 = *reinterpret_cast<const float4*>(W + (size_t)(k + 1) * 512);
        float4 w2 = *reinterpret_cast<const float4*>(W + (size_t)(k + 2) * 512);
        float4 w3 = *reinterpret_cast<const float4*>(W + (size_t)(k + 3) * 512);
#pragma unroll
        for (int r = 0; r < 16; ++r) {
            float4 a = *reinterpret_cast<const float4*>(&xs[r * 256 + k]);
            acc[r][0] += a.x * w0.x + a.y * w1.x + a.z * w2.x + a.w * w3.x;
            acc[r][1] += a.x * w0.y + a.y * w1.y + a.z * w2.y + a.w * w3.y;
            acc[r][2] += a.x * w0.z + a.y * w1.z + a.z * w2.z + a.w * w3.z;
            acc[r][3] += a.x * w0.w + a.y * w1.w + a.z * w2.w + a.w * w3.w;
        }
    }
    float* outp = (cb < 512) ? (xl1 + cb) : (xr1 + (cb - 512));
    for (int r = 0; r < 16; ++r) {
        float4 v = make_float4(acc[r][0], acc[r][1], acc[r][2], acc[r][3]);
        *reinterpret_cast<float4*>(outp + (size_t)(row0 + r) * 512) = v;
    }
}

// Fused edge+node layer 1: one block (512 thr = 8 waves) per node; wave = head.
__global__ __launch_bounds__(512) void k_node1f(const int* __restrict__ offs,
        const int* __restrict__ ssrc, const float* __restrict__ xl1,
        const float* __restrict__ xr1, const float* __restrict__ att1,
        const float* __restrict__ b1, float* __restrict__ h1) {
    constexpr int C = 8;                 // edges per chunk
    __shared__ int slds[MAXD1];
    int n = blockIdx.x;
    int t = threadIdx.x;                 // t = h*64 + lane
    int h = t >> 6, lane = t & 63;
    int beg = offs[n], dcnt = offs[n + 1] - beg;
    int cap = (dcnt < MAXD1) ? dcnt : MAXD1;
    for (int i = t; i < cap; i += 512) slds[i] = ssrc[beg + i];
    __syncthreads();
    int ej = lane >> 3;                  // edge within chunk (phase 1)
    int cg = lane & 7;                   // channel group of 8 (phase 1)
    // phase-1 lane constants: xr + att for channels h*64 + cg*8 .. +7
    const float* xrrow = xr1 + (size_t)n * 512 + h * 64 + cg * 8;
    float4 xra = *reinterpret_cast<const float4*>(xrrow);
    float4 xrb = *reinterpret_cast<const float4*>(xrrow + 4);
    const float* atrow = att1 + h * 64 + cg * 8;
    float4 ata = *reinterpret_cast<const float4*>(atrow);
    float4 atb = *reinterpret_cast<const float4*>(atrow + 4);
    float m = -1e30f, l = 0.f, acc = 0.f;
    for (int base = 0; base < dcnt; base += C) {
        // ---- phase 1: alphas for edges base..base+7 ----
        int i1 = base + ej;
        int i1c = (i1 < dcnt) ? i1 : (dcnt - 1);
        int sj = (i1c < MAXD1) ? slds[i1c] : ssrc[beg + i1c];
        const float* xlrow = xl1 + (size_t)sj * 512 + h * 64 + cg * 8;
        float4 xa = *reinterpret_cast<const float4*>(xlrow);
        float4 xb = *reinterpret_cast<const float4*>(xlrow + 4);
        float p = lrelu(xa.x + xra.x) * ata.x + lrelu(xa.y + xra.y) * ata.y
                + lrelu(xa.z + xra.z) * ata.z + lrelu(xa.w + xra.w) * ata.w
                + lrelu(xb.x + xrb.x) * atb.x + lrelu(xb.y + xrb.y) * atb.y
                + lrelu(xb.z + xrb.z) * atb.z + lrelu(xb.w + xrb.w) * atb.w;
        p += __shfl_xor(p, 1);
        p += __shfl_xor(p, 2);
        p += __shfl_xor(p, 4);           // alpha_j now in lanes 8j..8j+7
        float aj[C];
#pragma unroll
        for (int j = 0; j < C; ++j) aj[j] = __shfl(p, j * 8);
        float pm = -1e30f;
#pragma unroll
        for (int j = 0; j < C; ++j) {
            if (base + j >= dcnt) aj[j] = -1e30f;
            pm = fmaxf(pm, aj[j]);
        }
        float mn = fmaxf(m, pm);
        float sc = __expf(m - mn);       // first chunk: exp(-inf) = 0
        l *= sc; acc *= sc;
        m = mn;
        float w[C];
#pragma unroll
        for (int j = 0; j < C; ++j) {
            w[j] = __expf(aj[j] - mn);   // inactive: exp(-inf) = 0
            l += w[j];
        }
        // ---- phase 2: aggregation, lane = channel (rows L1-hot) ----
#pragma unroll
        for (int j = 0; j < C; ++j) {
            int i2 = base + j;
            int i2c = (i2 < dcnt) ? i2 : (dcnt - 1);   // w[j]=0 masks dups
            int s = (i2c < MAXD1) ? slds[i2c] : ssrc[beg + i2c];
            float xl = xl1[(size_t)s * 512 + h * 64 + lane];
            acc += w[j] * xl;
        }
    }
    float v = acc / (l + 1e-16f) + b1[t];
    v = (v > 0.f) ? v : expm1f(v);       // elu
    h1[(size_t)n * 512 + t] = v;
}

// ---------------- layer 2 ----------------

// 4 rows x 64 cols (W2l||W2r fused) per block, 256 threads, k-unroll x4.
__global__ __launch_bounds__(256) void k_gemm2(const float* __restrict__ h1,
        const float* __restrict__ Wl, const float* __restrict__ Wr,
        float* __restrict__ xw2) {
    __shared__ float hs[4 * 512];
    int t = threadIdx.x;
    int n0 = blockIdx.x * 4;
    const float4* hsrc = reinterpret_cast<const float4*>(h1 + (size_t)n0 * 512);
    float4* hdst = reinterpret_cast<float4*>(hs);
    for (int i = t; i < 512; i += 256) hdst[i] = hsrc[i];
    __syncthreads();
    int r = t >> 6, j = t & 63;
    const float* W = (j < 32) ? (Wl + j) : (Wr + (j - 32));
    float acc = 0.f;
    for (int k = 0; k < 512; k += 4) {
        float4 a = *reinterpret_cast<const float4*>(&hs[r * 512 + k]);
        acc += a.x * W[(size_t)(k + 0) * 32] + a.y * W[(size_t)(k + 1) * 32]
             + a.z * W[(size_t)(k + 2) * 32] + a.w * W[(size_t)(k + 3) * 32];
    }
    xw2[(size_t)(n0 + r) * 64 + j] = acc;
}

// Fused edge+node layer 2 + log_softmax: one wave per node (4 nodes/block).
// Phase 1: lane=(edge, 4-ch group) computes 8 alphas (3 shuffles).
// Phase 2: halves own edge parities with independent online state.
__global__ __launch_bounds__(256) void k_node2f(const int* __restrict__ offs,
        const int* __restrict__ ssrc, const float* __restrict__ xw2,
        const float* __restrict__ att2, const float* __restrict__ b2,
        float* __restrict__ out) {
    constexpr int C = 8;
    __shared__ int slds[4 * MAXD2];
    int t = threadIdx.x;
    int wv = t >> 6;
    int n = blockIdx.x * 4 + wv;
    int lane = t & 63;
    int beg = offs[n], dcnt = offs[n + 1] - beg;
    int cap = (dcnt < MAXD2) ? dcnt : MAXD2;
    int* sl = slds + wv * MAXD2;
    for (int i = lane; i < cap; i += 64) sl[i] = ssrc[beg + i];
    __syncthreads();
    int ej = lane >> 3;                  // phase-1 edge
    int cg = lane & 7;                   // phase-1 channel group of 4
    float4 xr = *reinterpret_cast<const float4*>(xw2 + (size_t)n * 64 + 32 + cg * 4);
    float4 at = *reinterpret_cast<const float4*>(att2 + cg * 4);
    int half = lane >> 5;                // phase-2 edge parity
    int c = lane & 31;                   // phase-2 channel
    float m = -1e30f, l = 0.f, acc = 0.f;
    for (int base = 0; base < dcnt; base += C) {
        int i1 = base + ej;
        int i1c = (i1 < dcnt) ? i1 : (dcnt - 1);
        int sj = (i1c < MAXD2) ? sl[i1c] : ssrc[beg + i1c];
        float4 xa = *reinterpret_cast<const float4*>(xw2 + (size_t)sj * 64 + cg * 4);
        float p = lrelu(xa.x + xr.x) * at.x + lrelu(xa.y + xr.y) * at.y
                + lrelu(xa.z + xr.z) * at.z + lrelu(xa.w + xr.w) * at.w;
        p += __shfl_xor(p, 1);
        p += __shfl_xor(p, 2);
        p += __shfl_xor(p, 4);
        float aj[C];
#pragma unroll
        for (int j = 0; j < C; ++j) aj[j] = __shfl(p, j * 8);
#pragma unroll
        for (int j = 0; j < C; ++j)
            if (base + j >= dcnt) aj[j] = -1e30f;
        // this half's 4 edges: j = 2*jj + half
        float pm = -1e30f;
#pragma unroll
        for (int jj = 0; jj < 4; ++jj) pm = fmaxf(pm, aj[2 * jj + half]);
        float mn = fmaxf(m, pm);
        float sc = __expf(m - mn);
        l *= sc; acc *= sc;
        m = mn;
#pragma unroll
        for (int jj = 0; jj < 4; ++jj) {
            int j = 2 * jj + half;
            float wj = __expf(aj[j] - mn);
            l += wj;
            int i2 = base + j;
            int i2c = (i2 < dcnt) ? i2 : (dcnt - 1);
            int s = (i2c < MAXD2) ? sl[i2c] : ssrc[beg + i2c];
            acc += wj * xw2[(size_t)s * 64 + c];
        }
    }
    // merge the two halves
    float m2   = __shfl_xor(m, 32);
    float l2   = __shfl_xor(l, 32);
    float acc2 = __shfl_xor(acc, 32);
    float M  = fmaxf(m, m2);
    float w1 = __expf(m - M), w2 = __expf(m2 - M);
    l   = l * w1 + l2 * w2;
    acc = acc * w1 + acc2 * w2;
    float v = acc / (l + 1e-16f) + b2[c];
    // log_softmax over 32 channels (identical in both halves)
    float mx = v;
#pragma unroll
    for (int o = 16; o; o >>= 1) mx = fmaxf(mx, __shfl_xor(mx, o));
    float se = __expf(v - mx);
#pragma unroll
    for (int o = 16; o; o >>= 1) se += __shfl_xor(se, o);
    float r = (v - mx) - __logf(se);
    if (half == 0) out[(size_t)n * 32 + c] = r;
}

// ---------------- launch ----------------

extern "C" void kernel_launch(void* const* d_in, const int* in_sizes, int n_in,
                              void* d_out, int out_size, void* d_ws, size_t ws_size,
                              hipStream_t stream) {
    (void)in_sizes; (void)n_in; (void)out_size; (void)ws_size;
    const float* x    = (const float*)d_in[0];
    const int*   ei   = (const int*)d_in[1];
    const float* W1l  = (const float*)d_in[2];
    const float* W1r  = (const float*)d_in[3];
    const float* att1 = (const float*)d_in[4];
    const float* b1   = (const float*)d_in[5];
    const float* W2l  = (const float*)d_in[6];
    const float* W2r  = (const float*)d_in[7];
    const float* att2 = (const float*)d_in[8];
    const float* b2   = (const float*)d_in[9];
    float* outp = (float*)d_out;

    char* ws = (char*)d_ws;
    size_t o = 0;
    auto alloc = [&](size_t bytes) {
        char* p = ws + o;
        o = (o + bytes + 255) & ~(size_t)255;
        return p;
    };
    float* xl1    = (float*)alloc((size_t)N_NODES * 512 * 4);
    float* xr1    = (float*)alloc((size_t)N_NODES * 512 * 4);
    float* h1     = (float*)alloc((size_t)N_NODES * 512 * 4);
    float* xw2    = (float*)alloc((size_t)N_NODES * 64 * 4);
    int*   deg    = (int*)alloc((size_t)N_NODES * 4);
    int*   cursor = (int*)alloc((size_t)N_NODES * 4);
    int*   offs   = (int*)alloc((size_t)(N_NODES + 1) * 4);
    int*   ssrc   = (int*)alloc((size_t)ET * 4);

    hipMemsetAsync(deg, 0, (size_t)N_NODES * 4, stream);
    hipMemsetAsync(cursor, 0, (size_t)N_NODES * 4, stream);

    k_count  <<<(ET + 255) / 256,   256, 0, stream>>>(ei, deg);
    k_scan   <<<1,                 1024, 0, stream>>>(deg, offs);
    k_scatter<<<(ET + 255) / 256,   256, 0, stream>>>(ei, offs, cursor, ssrc);
    k_gemm1  <<<N_NODES / 16,       256, 0, stream>>>(x, W1l, W1r, xl1, xr1);
    k_node1f <<<N_NODES,            512, 0, stream>>>(offs, ssrc, xl1, xr1, att1, b1, h1);
    k_gemm2  <<<N_NODES / 4,        256, 0, stream>>>(h1, W2l, W2r, xw2);
    k_node2f <<<N_NODES / 4,        256, 0, stream>>>(offs, ssrc, xw2, att2, b2, outp);
}

// Round 6
// 362.528 us; speedup vs baseline: 1.7106x; 1.2197x over previous
//
#include <hip/hip_runtime.h>
#include <hip/hip_bf16.h>

// GATv2 x2 on MI355X — fp32, fused attention, phase-split + LDS transpose.
//  Node kernels, per 8-edge chunk:
//   phase 1: lane=(edge, ch-group) loads the 8 rows ONCE, computes alphas
//            (3 xor-shuffles over 8 lanes), stashes the tile in per-wave LDS.
//   weights: cross-group max (3 shuffles), ONE exp per lane, 8 weights
//            published through a tiny per-wave LDS buffer.
//   phase 2: lane=channel reads the tile back from LDS (conflict-free,
//            wave-ordered DS => no barrier) and runs the online update.
//  No phase-2 global gather, no per-load 64-bit address VALU, 1/8th the exps.

constexpr int N_NODES = 10000;
constexpr int N_EDGES = 320000;
constexpr int ET      = N_EDGES + N_NODES;   // 330000 incl. self loops
constexpr float NEG_SLOPE = 0.2f;
constexpr int MAXD1 = 384;                   // LDS ssrc cache per node (layer1)
constexpr int MAXD2 = 160;                   // per node (layer2, 4 nodes/block)

__device__ __forceinline__ float lrelu(float a) {
    return (a > 0.f) ? a : NEG_SLOPE * a;
}

// ---------------- CSR build ----------------

__global__ void k_count(const int* __restrict__ ei, int* __restrict__ deg) {
    int e = blockIdx.x * 256 + threadIdx.x;
    if (e >= ET) return;
    int d = (e < N_EDGES) ? ei[N_EDGES + e] : (e - N_EDGES);
    atomicAdd(&deg[d], 1);
}

__global__ __launch_bounds__(1024) void k_scan(const int* __restrict__ deg,
                                               int* __restrict__ offs) {
    __shared__ int part[1024];
    const int CH = 10;                       // ceil(10000/1024)
    int t = threadIdx.x;
    int base = t * CH;
    int loc[CH];
    int s = 0;
    for (int i = 0; i < CH; ++i) {
        int idx = base + i;
        int v = (idx < N_NODES) ? deg[idx] : 0;
        loc[i] = s; s += v;
    }
    part[t] = s;
    __syncthreads();
    for (int o = 1; o < 1024; o <<= 1) {
        int add = (t >= o) ? part[t - o] : 0;
        __syncthreads();
        part[t] += add;
        __syncthreads();
    }
    int excl = part[t] - s;
    for (int i = 0; i < CH; ++i) {
        int idx = base + i;
        if (idx < N_NODES) offs[idx] = excl + loc[i];
    }
    if (t == 1023) offs[N_NODES] = part[1023];
}

__global__ void k_scatter(const int* __restrict__ ei, const int* __restrict__ offs,
                          int* __restrict__ cursor, int* __restrict__ ssrc) {
    int e = blockIdx.x * 256 + threadIdx.x;
    if (e >= ET) return;
    int s, d;
    if (e < N_EDGES) { s = ei[e]; d = ei[N_EDGES + e]; }
    else             { s = d = e - N_EDGES; }
    int pos = offs[d] + atomicAdd(&cursor[d], 1);
    ssrc[pos] = s;
}

// ---------------- layer 1 ----------------

// 16 rows x 1024 cols (W1l||W1r fused) per block, 256 threads, 4 cols/thread.
__global__ __launch_bounds__(256) void k_gemm1(const float* __restrict__ x,
        const float* __restrict__ Wl, const float* __restrict__ Wr,
        float* __restrict__ xl1, float* __restrict__ xr1) {
    __shared__ float xs[16 * 256];
    int t = threadIdx.x;
    int row0 = blockIdx.x * 16;
    const float4* xsrc = reinterpret_cast<const float4*>(x + (size_t)row0 * 256);
    float4* xdst = reinterpret_cast<float4*>(xs);
    for (int i = t; i < 16 * 64; i += 256) xdst[i] = xsrc[i];
    __syncthreads();
    int cb = t * 4;
    const float* W = (cb < 512) ? (Wl + cb) : (Wr + (cb - 512));
    float acc[16][4];
#pragma unroll
    for (int r = 0; r < 16; ++r)
        for (int j = 0; j < 4; ++j) acc[r][j] = 0.f;
    for (int k = 0; k < 256; k += 4) {
        float4 w0 = *reinterpret_cast<const float4*>(W + (size_t)(k + 0) * 512);
        float4 w1 = *reinterpret_cast<const float4*>(W + (size_t)(k + 1) * 512);
        float4 w2 = *reinterpret_cast<const float4*>(W + (size_t)(k + 2) * 512);
        float4 w3 = *reinterpret_cast<const float4*>(W + (size_t)(k + 3) * 512);
#pragma unroll
        for (int r = 0; r < 16; ++r) {
            float4 a = *reinterpret_cast<const float4*>(&xs[r * 256 + k]);
            acc[r][0] += a.x * w0.x + a.y * w1.x + a.z * w2.x + a.w * w3.x;
            acc[r][1] += a.x * w0.y + a.y * w1.y + a.z * w2.y + a.w * w3.y;
            acc[r][2] += a.x * w0.z + a.y * w1.z + a.z * w2.z + a.w * w3.z;
            acc[r][3] += a.x * w0.w + a.y * w1.w + a.z * w2.w + a.w * w3.w;
        }
    }
    float* outp = (cb < 512) ? (xl1 + cb) : (xr1 + (cb - 512));
    for (int r = 0; r < 16; ++r) {
        float4 v = make_float4(acc[r][0], acc[r][1], acc[r][2], acc[r][3]);
        *reinterpret_cast<float4*>(outp + (size_t)(row0 + r) * 512) = v;
    }
}

// Fused edge+node layer 1: one block (512 thr = 8 waves) per node; wave = head.
__global__ __launch_bounds__(512) void k_node1f(const int* __restrict__ offs,
        const int* __restrict__ ssrc, const float* __restrict__ xl1,
        const float* __restrict__ xr1, const float* __restrict__ att1,
        const float* __restrict__ b1, float* __restrict__ h1) {
    constexpr int C = 8;                 // edges per chunk
    __shared__ int slds[MAXD1];
    __shared__ float xt[8 * 520];        // per-wave 8x64 tile (+pad)
    __shared__ float wpub[8 * 8];        // per-wave 8 weights
    int n = blockIdx.x;
    int t = threadIdx.x;                 // t = h*64 + lane
    int h = t >> 6, lane = t & 63;
    int beg = offs[n], dcnt = offs[n + 1] - beg;
    int cap = (dcnt < MAXD1) ? dcnt : MAXD1;
    for (int i = t; i < cap; i += 512) slds[i] = ssrc[beg + i];
    __syncthreads();
    float* xtw = xt + h * 520;
    float* wbw = wpub + h * 8;
    int ej = lane >> 3;                  // edge within chunk (phase 1)
    int cg = lane & 7;                   // channel group of 8 (phase 1)
    const float* xrrow = xr1 + (size_t)n * 512 + h * 64 + cg * 8;
    float4 xra = *reinterpret_cast<const float4*>(xrrow);
    float4 xrb = *reinterpret_cast<const float4*>(xrrow + 4);
    const float* atrow = att1 + h * 64 + cg * 8;
    float4 ata = *reinterpret_cast<const float4*>(atrow);
    float4 atb = *reinterpret_cast<const float4*>(atrow + 4);
    float m = -1e30f, l = 0.f, acc = 0.f;
    for (int base = 0; base < dcnt; base += C) {
        // ---- phase 1: load 8 rows once, alphas via 3 xor-shuffles ----
        int i1 = base + ej;
        int i1c = (i1 < dcnt) ? i1 : (dcnt - 1);
        int sj = (i1c < MAXD1) ? slds[i1c] : ssrc[beg + i1c];
        const float* xlrow = xl1 + (size_t)sj * 512 + h * 64 + cg * 8;
        float4 xa = *reinterpret_cast<const float4*>(xlrow);
        float4 xb = *reinterpret_cast<const float4*>(xlrow + 4);
        *reinterpret_cast<float4*>(&xtw[ej * 64 + cg * 8])     = xa;
        *reinterpret_cast<float4*>(&xtw[ej * 64 + cg * 8 + 4]) = xb;
        float p = lrelu(xa.x + xra.x) * ata.x + lrelu(xa.y + xra.y) * ata.y
                + lrelu(xa.z + xra.z) * ata.z + lrelu(xa.w + xra.w) * ata.w
                + lrelu(xb.x + xrb.x) * atb.x + lrelu(xb.y + xrb.y) * atb.y
                + lrelu(xb.z + xrb.z) * atb.z + lrelu(xb.w + xrb.w) * atb.w;
        p += __shfl_xor(p, 1);
        p += __shfl_xor(p, 2);
        p += __shfl_xor(p, 4);           // group's alpha in all 8 lanes
        if (i1 >= dcnt) p = -1e30f;
        // ---- chunk max + one exp per lane, publish 8 weights ----
        float pm = p;
        pm = fmaxf(pm, __shfl_xor(pm, 8));
        pm = fmaxf(pm, __shfl_xor(pm, 16));
        pm = fmaxf(pm, __shfl_xor(pm, 32));
        float mn = fmaxf(m, pm);
        float w = __expf(p - mn);        // own edge's weight (0 if inactive)
        if (cg == 0) wbw[ej] = w;
        float sc = __expf(m - mn);       // first chunk: exp(-inf) = 0
        l *= sc; acc *= sc; m = mn;
        // ---- phase 2: lane = channel, tile + weights from LDS ----
        float4 w0 = *reinterpret_cast<const float4*>(&wbw[0]);
        float4 w1 = *reinterpret_cast<const float4*>(&wbw[4]);
        l += (w0.x + w0.y + w0.z + w0.w) + (w1.x + w1.y + w1.z + w1.w);
        acc += w0.x * xtw[0 * 64 + lane] + w0.y * xtw[1 * 64 + lane]
             + w0.z * xtw[2 * 64 + lane] + w0.w * xtw[3 * 64 + lane]
             + w1.x * xtw[4 * 64 + lane] + w1.y * xtw[5 * 64 + lane]
             + w1.z * xtw[6 * 64 + lane] + w1.w * xtw[7 * 64 + lane];
    }
    float v = acc / (l + 1e-16f) + b1[t];
    v = (v > 0.f) ? v : expm1f(v);       // elu
    h1[(size_t)n * 512 + t] = v;
}

// ---------------- layer 2 ----------------

// 4 rows x 64 cols (W2l||W2r fused) per block, 256 threads, k-unroll x4.
__global__ __launch_bounds__(256) void k_gemm2(const float* __restrict__ h1,
        const float* __restrict__ Wl, const float* __restrict__ Wr,
        float* __restrict__ xw2) {
    __shared__ float hs[4 * 512];
    int t = threadIdx.x;
    int n0 = blockIdx.x * 4;
    const float4* hsrc = reinterpret_cast<const float4*>(h1 + (size_t)n0 * 512);
    float4* hdst = reinterpret_cast<float4*>(hs);
    for (int i = t; i < 512; i += 256) hdst[i] = hsrc[i];
    __syncthreads();
    int r = t >> 6, j = t & 63;
    const float* W = (j < 32) ? (Wl + j) : (Wr + (j - 32));
    float acc = 0.f;
    for (int k = 0; k < 512; k += 4) {
        float4 a = *reinterpret_cast<const float4*>(&hs[r * 512 + k]);
        acc += a.x * W[(size_t)(k + 0) * 32] + a.y * W[(size_t)(k + 1) * 32]
             + a.z * W[(size_t)(k + 2) * 32] + a.w * W[(size_t)(k + 3) * 32];
    }
    xw2[(size_t)(n0 + r) * 64 + j] = acc;
}

// Fused edge+node layer 2 + log_softmax: one wave per node (4 nodes/block).
// Same phase-split + LDS-transpose; single wave-wide online state
// (lanes 32-63 duplicate lanes 0-31 in phase 2; only lanes <32 store).
__global__ __launch_bounds__(256) void k_node2f(const int* __restrict__ offs,
        const int* __restrict__ ssrc, const float* __restrict__ xw2,
        const float* __restrict__ att2, const float* __restrict__ b2,
        float* __restrict__ out) {
    constexpr int C = 8;
    __shared__ int slds[4 * MAXD2];
    __shared__ float xt[4 * 260];        // per-wave 8x32 tile (+pad)
    __shared__ float wpub[4 * 8];
    int t = threadIdx.x;
    int wv = t >> 6;
    int n = blockIdx.x * 4 + wv;
    int lane = t & 63;
    int beg = offs[n], dcnt = offs[n + 1] - beg;
    int cap = (dcnt < MAXD2) ? dcnt : MAXD2;
    int* sl = slds + wv * MAXD2;
    for (int i = lane; i < cap; i += 64) sl[i] = ssrc[beg + i];
    __syncthreads();
    float* xtw = xt + wv * 260;
    float* wbw = wpub + wv * 8;
    int ej = lane >> 3;                  // phase-1 edge
    int cg = lane & 7;                   // phase-1 channel group of 4
    int c = lane & 31;                   // phase-2 channel
    float4 xr = *reinterpret_cast<const float4*>(xw2 + (size_t)n * 64 + 32 + cg * 4);
    float4 at = *reinterpret_cast<const float4*>(att2 + cg * 4);
    float m = -1e30f, l = 0.f, acc = 0.f;
    for (int base = 0; base < dcnt; base += C) {
        int i1 = base + ej;
        int i1c = (i1 < dcnt) ? i1 : (dcnt - 1);
        int sj = (i1c < MAXD2) ? sl[i1c] : ssrc[beg + i1c];
        float4 xa = *reinterpret_cast<const float4*>(xw2 + (size_t)sj * 64 + cg * 4);
        *reinterpret_cast<float4*>(&xtw[ej * 32 + cg * 4]) = xa;
        float p = lrelu(xa.x + xr.x) * at.x + lrelu(xa.y + xr.y) * at.y
                + lrelu(xa.z + xr.z) * at.z + lrelu(xa.w + xr.w) * at.w;
        p += __shfl_xor(p, 1);
        p += __shfl_xor(p, 2);
        p += __shfl_xor(p, 4);
        if (i1 >= dcnt) p = -1e30f;
        float pm = p;
        pm = fmaxf(pm, __shfl_xor(pm, 8));
        pm = fmaxf(pm, __shfl_xor(pm, 16));
        pm = fmaxf(pm, __shfl_xor(pm, 32));
        float mn = fmaxf(m, pm);
        float w = __expf(p - mn);
        if (cg == 0) wbw[ej] = w;
        float sc = __expf(m - mn);
        l *= sc; acc *= sc; m = mn;
        float4 w0 = *reinterpret_cast<const float4*>(&wbw[0]);
        float4 w1 = *reinterpret_cast<const float4*>(&wbw[4]);
        l += (w0.x + w0.y + w0.z + w0.w) + (w1.x + w1.y + w1.z + w1.w);
        acc += w0.x * xtw[0 * 32 + c] + w0.y * xtw[1 * 32 + c]
             + w0.z * xtw[2 * 32 + c] + w0.w * xtw[3 * 32 + c]
             + w1.x * xtw[4 * 32 + c] + w1.y * xtw[5 * 32 + c]
             + w1.z * xtw[6 * 32 + c] + w1.w * xtw[7 * 32 + c];
    }
    float v = acc / (l + 1e-16f) + b2[c];
    // log_softmax over 32 channels (lanes 32-63 hold identical duplicates)
    float mx = v;
#pragma unroll
    for (int o = 16; o; o >>= 1) mx = fmaxf(mx, __shfl_xor(mx, o));
    float se = __expf(v - mx);
#pragma unroll
    for (int o = 16; o; o >>= 1) se += __shfl_xor(se, o);
    float r = (v - mx) - __logf(se);
    if (lane < 32) out[(size_t)n * 32 + c] = r;
}

// ---------------- launch ----------------

extern "C" void kernel_launch(void* const* d_in, const int* in_sizes, int n_in,
                              void* d_out, int out_size, void* d_ws, size_t ws_size,
                              hipStream_t stream) {
    (void)in_sizes; (void)n_in; (void)out_size; (void)ws_size;
    const float* x    = (const float*)d_in[0];
    const int*   ei   = (const int*)d_in[1];
    const float* W1l  = (const float*)d_in[2];
    const float* W1r  = (const float*)d_in[3];
    const float* att1 = (const float*)d_in[4];
    const float* b1   = (const float*)d_in[5];
    const float* W2l  = (const float*)d_in[6];
    const float* W2r  = (const float*)d_in[7];
    const float* att2 = (const float*)d_in[8];
    const float* b2   = (const float*)d_in[9];
    float* outp = (float*)d_out;

    char* ws = (char*)d_ws;
    size_t o = 0;
    auto alloc = [&](size_t bytes) {
        char* p = ws + o;
        o = (o + bytes + 255) & ~(size_t)255;
        return p;
    };
    float* xl1    = (float*)alloc((size_t)N_NODES * 512 * 4);
    float* xr1    = (float*)alloc((size_t)N_NODES * 512 * 4);
    float* h1     = (float*)alloc((size_t)N_NODES * 512 * 4);
    float* xw2    = (float*)alloc((size_t)N_NODES * 64 * 4);
    int*   deg    = (int*)alloc((size_t)N_NODES * 4);
    int*   cursor = (int*)alloc((size_t)N_NODES * 4);
    int*   offs   = (int*)alloc((size_t)(N_NODES + 1) * 4);
    int*   ssrc   = (int*)alloc((size_t)ET * 4);

    hipMemsetAsync(deg, 0, (size_t)N_NODES * 4, stream);
    hipMemsetAsync(cursor, 0, (size_t)N_NODES * 4, stream);

    k_count  <<<(ET + 255) / 256,   256, 0, stream>>>(ei, deg);
    k_scan   <<<1,                 1024, 0, stream>>>(deg, offs);
    k_scatter<<<(ET + 255) / 256,   256, 0, stream>>>(ei, offs, cursor, ssrc);
    k_gemm1  <<<N_NODES / 16,       256, 0, stream>>>(x, W1l, W1r, xl1, xr1);
    k_node1f <<<N_NODES,            512, 0, stream>>>(offs, ssrc, xl1, xr1, att1, b1, h1);
    k_gemm2  <<<N_NODES / 4,        256, 0, stream>>>(h1, W2l, W2r, xw2);
    k_node2f <<<N_NODES / 4,        256, 0, stream>>>(offs, ssrc, xw2, att2, b2, outp);
}

// Round 7
// 313.707 us; speedup vs baseline: 1.9768x; 1.1556x over previous
//
#include <hip/hip_runtime.h>
#include <hip/hip_bf16.h>

// GATv2 x2 on MI355X — fp32 pipeline, MFMA gemm1 via split-bf16.
//  gemm1 (x@W1l | x@W1r, K=256) is computed as ONE bf16 MFMA GEMM with
//  K'=768: A' = [Ah | Al | Ah], B' = [Bh ; Bh ; Bl] where X = Xh + Xl is the
//  bf16 hi/lo decomposition. This yields Ah·Bh + Al·Bh + Ah·Bl — fp32-level
//  accuracy (dropped term ~2^-18) at matrix-core speed.
//  Node kernels: phase-split online softmax + per-wave LDS transpose (R6).

constexpr int N_NODES = 10000;
constexpr int N_EDGES = 320000;
constexpr int ET      = N_EDGES + N_NODES;   // 330000 incl. self loops
constexpr float NEG_SLOPE = 0.2f;
constexpr int MAXD1 = 384;                   // LDS ssrc cache per node (layer1)
constexpr int MAXD2 = 160;                   // per node (layer2, 4 nodes/block)

typedef __attribute__((ext_vector_type(8))) short short8;
typedef __attribute__((ext_vector_type(4))) float floatx4;

__device__ __forceinline__ float lrelu(float a) {
    return (a > 0.f) ? a : NEG_SLOPE * a;
}
__device__ __forceinline__ unsigned short f2bf(float f) {   // RNE
    unsigned u = __float_as_uint(f);
    unsigned r = u + 0x7FFFu + ((u >> 16) & 1u);
    return (unsigned short)(r >> 16);
}
__device__ __forceinline__ float bf2f(unsigned short h) {
    return __uint_as_float((unsigned)h << 16);
}

// ---------------- CSR build ----------------

__global__ void k_count(const int* __restrict__ ei, int* __restrict__ deg) {
    int e = blockIdx.x * 256 + threadIdx.x;
    if (e >= ET) return;
    int d = (e < N_EDGES) ? ei[N_EDGES + e] : (e - N_EDGES);
    atomicAdd(&deg[d], 1);
}

__global__ __launch_bounds__(1024) void k_scan(const int* __restrict__ deg,
                                               int* __restrict__ offs) {
    __shared__ int part[1024];
    const int CH = 10;                       // ceil(10000/1024)
    int t = threadIdx.x;
    int base = t * CH;
    int loc[CH];
    int s = 0;
    for (int i = 0; i < CH; ++i) {
        int idx = base + i;
        int v = (idx < N_NODES) ? deg[idx] : 0;
        loc[i] = s; s += v;
    }
    part[t] = s;
    __syncthreads();
    for (int o = 1; o < 1024; o <<= 1) {
        int add = (t >= o) ? part[t - o] : 0;
        __syncthreads();
        part[t] += add;
        __syncthreads();
    }
    int excl = part[t] - s;
    for (int i = 0; i < CH; ++i) {
        int idx = base + i;
        if (idx < N_NODES) offs[idx] = excl + loc[i];
    }
    if (t == 1023) offs[N_NODES] = part[1023];
}

__global__ void k_scatter(const int* __restrict__ ei, const int* __restrict__ offs,
                          int* __restrict__ cursor, int* __restrict__ ssrc) {
    int e = blockIdx.x * 256 + threadIdx.x;
    if (e >= ET) return;
    int s, d;
    if (e < N_EDGES) { s = ei[e]; d = ei[N_EDGES + e]; }
    else             { s = d = e - N_EDGES; }
    int pos = offs[d] + atomicAdd(&cursor[d], 1);
    ssrc[pos] = s;
}

// ---------------- layer 1: split-bf16 conversion + MFMA GEMM ----------------

// x[10000,256] fp32 -> A'[10000,768] bf16: segs [hi | lo | hi]
__global__ __launch_bounds__(256) void k_conv_x(const float* __restrict__ x,
        unsigned short* __restrict__ A) {
    int idx = blockIdx.x * 256 + threadIdx.x;       // N_NODES*64 threads
    if (idx >= N_NODES * 64) return;
    int m = idx >> 6, kg = (idx & 63) << 2;
    float4 v = *reinterpret_cast<const float4*>(x + (size_t)m * 256 + kg);
    ushort4 hi = make_ushort4(f2bf(v.x), f2bf(v.y), f2bf(v.z), f2bf(v.w));
    ushort4 lo = make_ushort4(f2bf(v.x - bf2f(hi.x)), f2bf(v.y - bf2f(hi.y)),
                              f2bf(v.z - bf2f(hi.z)), f2bf(v.w - bf2f(hi.w)));
    size_t base = (size_t)m * 768 + kg;
    *reinterpret_cast<ushort4*>(A + base)       = hi;
    *reinterpret_cast<ushort4*>(A + base + 256) = lo;
    *reinterpret_cast<ushort4*>(A + base + 512) = hi;
}

// W1l/W1r [256,512] fp32 -> Bt[1024,768] bf16 (transposed): segs [hi | hi | lo]
__global__ __launch_bounds__(256) void k_conv_w(const float* __restrict__ Wl,
        const float* __restrict__ Wr, unsigned short* __restrict__ Bt) {
    int idx = blockIdx.x * 256 + threadIdx.x;       // 1024*64 threads
    if (idx >= 1024 * 64) return;
    int n = idx >> 6, kg = (idx & 63) << 2;
    const float* src = (n < 512) ? (Wl + n) : (Wr + (n - 512));
    float v0 = src[(size_t)(kg + 0) * 512];
    float v1 = src[(size_t)(kg + 1) * 512];
    float v2 = src[(size_t)(kg + 2) * 512];
    float v3 = src[(size_t)(kg + 3) * 512];
    ushort4 hi = make_ushort4(f2bf(v0), f2bf(v1), f2bf(v2), f2bf(v3));
    ushort4 lo = make_ushort4(f2bf(v0 - bf2f(hi.x)), f2bf(v1 - bf2f(hi.y)),
                              f2bf(v2 - bf2f(hi.z)), f2bf(v3 - bf2f(hi.w)));
    size_t base = (size_t)n * 768 + kg;
    *reinterpret_cast<ushort4*>(Bt + base)       = hi;
    *reinterpret_cast<ushort4*>(Bt + base + 256) = hi;
    *reinterpret_cast<ushort4*>(Bt + base + 512) = lo;
}

// 128x128 tile MFMA GEMM, M=10000 N=1024 K=768, grid (79,8), 4 waves/block.
// Wave (wm,wn) owns a 64x64 quadrant = 4x4 of 16x16x32 bf16 MFMAs.
__global__ __launch_bounds__(256) void k_mfma1(const unsigned short* __restrict__ A,
        const unsigned short* __restrict__ Bt, float* __restrict__ xl1,
        float* __restrict__ xr1) {
    __shared__ unsigned short As[128 * 40];   // stride 40 (80B): 2-way max = free
    __shared__ unsigned short Bs[128 * 40];
    int t = threadIdx.x;
    int wave = t >> 6, L = t & 63;
    int wm = wave & 1, wn = wave >> 1;
    int row0 = blockIdx.x * 128, n0 = blockIdx.y * 128;
    int q = L >> 4, rr = L & 15;
    floatx4 acc[4][4];
#pragma unroll
    for (int i = 0; i < 4; ++i)
#pragma unroll
        for (int j = 0; j < 4; ++j) acc[i][j] = (floatx4){0.f, 0.f, 0.f, 0.f};
    // staging assignments: 512 16B-chunks per 128x32 tile, 2 per thread
    int ra = t >> 2,        ka = (t & 3) * 8;
    int rb = (t + 256) >> 2, kb = ((t + 256) & 3) * 8;
    int gma = row0 + ra; gma = (gma < N_NODES) ? gma : (N_NODES - 1);
    int gmb = row0 + rb; gmb = (gmb < N_NODES) ? gmb : (N_NODES - 1);
    for (int kc = 0; kc < 768; kc += 32) {
        __syncthreads();
        *reinterpret_cast<uint4*>(&As[ra * 40 + ka]) =
            *reinterpret_cast<const uint4*>(A + (size_t)gma * 768 + kc + ka);
        *reinterpret_cast<uint4*>(&As[rb * 40 + kb]) =
            *reinterpret_cast<const uint4*>(A + (size_t)gmb * 768 + kc + kb);
        *reinterpret_cast<uint4*>(&Bs[ra * 40 + ka]) =
            *reinterpret_cast<const uint4*>(Bt + (size_t)(n0 + ra) * 768 + kc + ka);
        *reinterpret_cast<uint4*>(&Bs[rb * 40 + kb]) =
            *reinterpret_cast<const uint4*>(Bt + (size_t)(n0 + rb) * 768 + kc + kb);
        __syncthreads();
        short8 af[4], bf[4];
#pragma unroll
        for (int st = 0; st < 4; ++st)
            af[st] = *reinterpret_cast<const short8*>(
                &As[(wm * 64 + st * 16 + rr) * 40 + q * 8]);
#pragma unroll
        for (int st = 0; st < 4; ++st)
            bf[st] = *reinterpret_cast<const short8*>(
                &Bs[(wn * 64 + st * 16 + rr) * 40 + q * 8]);
#pragma unroll
        for (int i = 0; i < 4; ++i)
#pragma unroll
            for (int j = 0; j < 4; ++j)
                acc[i][j] = __builtin_amdgcn_mfma_f32_16x16x32_bf16(
                    af[i], bf[j], acc[i][j], 0, 0, 0);
    }
    // epilogue: C/D layout col=lane&15, row=(lane>>4)*4+reg  [m89/m91]
#pragma unroll
    for (int j = 0; j < 4; ++j) {
        int gc = n0 + wn * 64 + j * 16 + rr;
        float* dst = (gc < 512) ? xl1 : xr1;
        int col = (gc < 512) ? gc : (gc - 512);
#pragma unroll
        for (int i = 0; i < 4; ++i) {
#pragma unroll
            for (int r = 0; r < 4; ++r) {
                int gr = row0 + wm * 64 + i * 16 + q * 4 + r;
                if (gr < N_NODES) dst[(size_t)gr * 512 + col] = acc[i][j][r];
            }
        }
    }
}

// Fused edge+node layer 1: one block (512 thr = 8 waves) per node; wave = head.
__global__ __launch_bounds__(512) void k_node1f(const int* __restrict__ offs,
        const int* __restrict__ ssrc, const float* __restrict__ xl1,
        const float* __restrict__ xr1, const float* __restrict__ att1,
        const float* __restrict__ b1, float* __restrict__ h1) {
    constexpr int C = 8;                 // edges per chunk
    __shared__ int slds[MAXD1];
    __shared__ float xt[8 * 520];        // per-wave 8x64 tile (+pad)
    __shared__ float wpub[8 * 8];        // per-wave 8 weights
    int n = blockIdx.x;
    int t = threadIdx.x;                 // t = h*64 + lane
    int h = t >> 6, lane = t & 63;
    int beg = offs[n], dcnt = offs[n + 1] - beg;
    int cap = (dcnt < MAXD1) ? dcnt : MAXD1;
    for (int i = t; i < cap; i += 512) slds[i] = ssrc[beg + i];
    __syncthreads();
    float* xtw = xt + h * 520;
    float* wbw = wpub + h * 8;
    int ej = lane >> 3;                  // edge within chunk (phase 1)
    int cg = lane & 7;                   // channel group of 8 (phase 1)
    const float* xrrow = xr1 + (size_t)n * 512 + h * 64 + cg * 8;
    float4 xra = *reinterpret_cast<const float4*>(xrrow);
    float4 xrb = *reinterpret_cast<const float4*>(xrrow + 4);
    const float* atrow = att1 + h * 64 + cg * 8;
    float4 ata = *reinterpret_cast<const float4*>(atrow);
    float4 atb = *reinterpret_cast<const float4*>(atrow + 4);
    float m = -1e30f, l = 0.f, acc = 0.f;
    for (int base = 0; base < dcnt; base += C) {
        // ---- phase 1: load 8 rows once, alphas via 3 xor-shuffles ----
        int i1 = base + ej;
        int i1c = (i1 < dcnt) ? i1 : (dcnt - 1);
        int sj = (i1c < MAXD1) ? slds[i1c] : ssrc[beg + i1c];
        const float* xlrow = xl1 + (size_t)sj * 512 + h * 64 + cg * 8;
        float4 xa = *reinterpret_cast<const float4*>(xlrow);
        float4 xb = *reinterpret_cast<const float4*>(xlrow + 4);
        *reinterpret_cast<float4*>(&xtw[ej * 64 + cg * 8])     = xa;
        *reinterpret_cast<float4*>(&xtw[ej * 64 + cg * 8 + 4]) = xb;
        float p = lrelu(xa.x + xra.x) * ata.x + lrelu(xa.y + xra.y) * ata.y
                + lrelu(xa.z + xra.z) * ata.z + lrelu(xa.w + xra.w) * ata.w
                + lrelu(xb.x + xrb.x) * atb.x + lrelu(xb.y + xrb.y) * atb.y
                + lrelu(xb.z + xrb.z) * atb.z + lrelu(xb.w + xrb.w) * atb.w;
        p += __shfl_xor(p, 1);
        p += __shfl_xor(p, 2);
        p += __shfl_xor(p, 4);           // group's alpha in all 8 lanes
        if (i1 >= dcnt) p = -1e30f;
        // ---- chunk max + one exp per lane, publish 8 weights ----
        float pm = p;
        pm = fmaxf(pm, __shfl_xor(pm, 8));
        pm = fmaxf(pm, __shfl_xor(pm, 16));
        pm = fmaxf(pm, __shfl_xor(pm, 32));
        float mn = fmaxf(m, pm);
        float w = __expf(p - mn);        // own edge's weight (0 if inactive)
        if (cg == 0) wbw[ej] = w;
        float sc = __expf(m - mn);       // first chunk: exp(-inf) = 0
        l *= sc; acc *= sc; m = mn;
        // ---- phase 2: lane = channel, tile + weights from LDS ----
        float4 w0 = *reinterpret_cast<const float4*>(&wbw[0]);
        float4 w1 = *reinterpret_cast<const float4*>(&wbw[4]);
        l += (w0.x + w0.y + w0.z + w0.w) + (w1.x + w1.y + w1.z + w1.w);
        acc += w0.x * xtw[0 * 64 + lane] + w0.y * xtw[1 * 64 + lane]
             + w0.z * xtw[2 * 64 + lane] + w0.w * xtw[3 * 64 + lane]
             + w1.x * xtw[4 * 64 + lane] + w1.y * xtw[5 * 64 + lane]
             + w1.z * xtw[6 * 64 + lane] + w1.w * xtw[7 * 64 + lane];
    }
    float v = acc / (l + 1e-16f) + b1[t];
    v = (v > 0.f) ? v : expm1f(v);       // elu
    h1[(size_t)n * 512 + t] = v;
}

// ---------------- layer 2 ----------------

// 4 rows x 64 cols (W2l||W2r fused) per block, 256 threads, k-unroll x4.
__global__ __launch_bounds__(256) void k_gemm2(const float* __restrict__ h1,
        const float* __restrict__ Wl, const float* __restrict__ Wr,
        float* __restrict__ xw2) {
    __shared__ float hs[4 * 512];
    int t = threadIdx.x;
    int n0 = blockIdx.x * 4;
    const float4* hsrc = reinterpret_cast<const float4*>(h1 + (size_t)n0 * 512);
    float4* hdst = reinterpret_cast<float4*>(hs);
    for (int i = t; i < 512; i += 256) hdst[i] = hsrc[i];
    __syncthreads();
    int r = t >> 6, j = t & 63;
    const float* W = (j < 32) ? (Wl + j) : (Wr + (j - 32));
    float acc = 0.f;
    for (int k = 0; k < 512; k += 4) {
        float4 a = *reinterpret_cast<const float4*>(&hs[r * 512 + k]);
        acc += a.x * W[(size_t)(k + 0) * 32] + a.y * W[(size_t)(k + 1) * 32]
             + a.z * W[(size_t)(k + 2) * 32] + a.w * W[(size_t)(k + 3) * 32];
    }
    xw2[(size_t)(n0 + r) * 64 + j] = acc;
}

// Fused edge+node layer 2 + log_softmax: one wave per node (4 nodes/block).
__global__ __launch_bounds__(256) void k_node2f(const int* __restrict__ offs,
        const int* __restrict__ ssrc, const float* __restrict__ xw2,
        const float* __restrict__ att2, const float* __restrict__ b2,
        float* __restrict__ out) {
    constexpr int C = 8;
    __shared__ int slds[4 * MAXD2];
    __shared__ float xt[4 * 260];        // per-wave 8x32 tile (+pad)
    __shared__ float wpub[4 * 8];
    int t = threadIdx.x;
    int wv = t >> 6;
    int n = blockIdx.x * 4 + wv;
    int lane = t & 63;
    int beg = offs[n], dcnt = offs[n + 1] - beg;
    int cap = (dcnt < MAXD2) ? dcnt : MAXD2;
    int* sl = slds + wv * MAXD2;
    for (int i = lane; i < cap; i += 64) sl[i] = ssrc[beg + i];
    __syncthreads();
    float* xtw = xt + wv * 260;
    float* wbw = wpub + wv * 8;
    int ej = lane >> 3;                  // phase-1 edge
    int cg = lane & 7;                   // phase-1 channel group of 4
    int c = lane & 31;                   // phase-2 channel
    float4 xr = *reinterpret_cast<const float4*>(xw2 + (size_t)n * 64 + 32 + cg * 4);
    float4 at = *reinterpret_cast<const float4*>(att2 + cg * 4);
    float m = -1e30f, l = 0.f, acc = 0.f;
    for (int base = 0; base < dcnt; base += C) {
        int i1 = base + ej;
        int i1c = (i1 < dcnt) ? i1 : (dcnt - 1);
        int sj = (i1c < MAXD2) ? sl[i1c] : ssrc[beg + i1c];
        float4 xa = *reinterpret_cast<const float4*>(xw2 + (size_t)sj * 64 + cg * 4);
        *reinterpret_cast<float4*>(&xtw[ej * 32 + cg * 4]) = xa;
        float p = lrelu(xa.x + xr.x) * at.x + lrelu(xa.y + xr.y) * at.y
                + lrelu(xa.z + xr.z) * at.z + lrelu(xa.w + xr.w) * at.w;
        p += __shfl_xor(p, 1);
        p += __shfl_xor(p, 2);
        p += __shfl_xor(p, 4);
        if (i1 >= dcnt) p = -1e30f;
        float pm = p;
        pm = fmaxf(pm, __shfl_xor(pm, 8));
        pm = fmaxf(pm, __shfl_xor(pm, 16));
        pm = fmaxf(pm, __shfl_xor(pm, 32));
        float mn = fmaxf(m, pm);
        float w = __expf(p - mn);
        if (cg == 0) wbw[ej] = w;
        float sc = __expf(m - mn);
        l *= sc; acc *= sc; m = mn;
        float4 w0 = *reinterpret_cast<const float4*>(&wbw[0]);
        float4 w1 = *reinterpret_cast<const float4*>(&wbw[4]);
        l += (w0.x + w0.y + w0.z + w0.w) + (w1.x + w1.y + w1.z + w1.w);
        acc += w0.x * xtw[0 * 32 + c] + w0.y * xtw[1 * 32 + c]
             + w0.z * xtw[2 * 32 + c] + w0.w * xtw[3 * 32 + c]
             + w1.x * xtw[4 * 32 + c] + w1.y * xtw[5 * 32 + c]
             + w1.z * xtw[6 * 32 + c] + w1.w * xtw[7 * 32 + c];
    }
    float v = acc / (l + 1e-16f) + b2[c];
    // log_softmax over 32 channels (lanes 32-63 hold identical duplicates)
    float mx = v;
#pragma unroll
    for (int o = 16; o; o >>= 1) mx = fmaxf(mx, __shfl_xor(mx, o));
    float se = __expf(v - mx);
#pragma unroll
    for (int o = 16; o; o >>= 1) se += __shfl_xor(se, o);
    float r = (v - mx) - __logf(se);
    if (lane < 32) out[(size_t)n * 32 + c] = r;
}

// ---------------- launch ----------------

extern "C" void kernel_launch(void* const* d_in, const int* in_sizes, int n_in,
                              void* d_out, int out_size, void* d_ws, size_t ws_size,
                              hipStream_t stream) {
    (void)in_sizes; (void)n_in; (void)out_size; (void)ws_size;
    const float* x    = (const float*)d_in[0];
    const int*   ei   = (const int*)d_in[1];
    const float* W1l  = (const float*)d_in[2];
    const float* W1r  = (const float*)d_in[3];
    const float* att1 = (const float*)d_in[4];
    const float* b1   = (const float*)d_in[5];
    const float* W2l  = (const float*)d_in[6];
    const float* W2r  = (const float*)d_in[7];
    const float* att2 = (const float*)d_in[8];
    const float* b2   = (const float*)d_in[9];
    float* outp = (float*)d_out;

    char* ws = (char*)d_ws;
    size_t o = 0;
    auto alloc = [&](size_t bytes) {
        char* p = ws + o;
        o = (o + bytes + 255) & ~(size_t)255;
        return p;
    };
    float* xl1    = (float*)alloc((size_t)N_NODES * 512 * 4);
    float* xr1    = (float*)alloc((size_t)N_NODES * 512 * 4);
    float* h1     = (float*)alloc((size_t)N_NODES * 512 * 4);
    float* xw2    = (float*)alloc((size_t)N_NODES * 64 * 4);
    unsigned short* Abf = (unsigned short*)alloc((size_t)N_NODES * 768 * 2);
    unsigned short* Bbf = (unsigned short*)alloc((size_t)1024 * 768 * 2);
    int*   deg    = (int*)alloc((size_t)N_NODES * 4);
    int*   cursor = (int*)alloc((size_t)N_NODES * 4);
    int*   offs   = (int*)alloc((size_t)(N_NODES + 1) * 4);
    int*   ssrc   = (int*)alloc((size_t)ET * 4);
    // total ~82 MB of d_ws

    hipMemsetAsync(deg, 0, (size_t)N_NODES * 4, stream);
    hipMemsetAsync(cursor, 0, (size_t)N_NODES * 4, stream);

    k_count  <<<(ET + 255) / 256,      256, 0, stream>>>(ei, deg);
    k_scan   <<<1,                    1024, 0, stream>>>(deg, offs);
    k_scatter<<<(ET + 255) / 256,      256, 0, stream>>>(ei, offs, cursor, ssrc);
    k_conv_x <<<(N_NODES * 64 + 255) / 256, 256, 0, stream>>>(x, Abf);
    k_conv_w <<<(1024 * 64 + 255) / 256,    256, 0, stream>>>(W1l, W1r, Bbf);
    k_mfma1  <<<dim3(79, 8),           256, 0, stream>>>(Abf, Bbf, xl1, xr1);
    k_node1f <<<N_NODES,               512, 0, stream>>>(offs, ssrc, xl1, xr1, att1, b1, h1);
    k_gemm2  <<<N_NODES / 4,           256, 0, stream>>>(h1, W2l, W2r, xw2);
    k_node2f <<<N_NODES / 4,           256, 0, stream>>>(offs, ssrc, xw2, att2, b2, outp);
}